// Round 10
// baseline (3762.490 us; speedup 1.0000x reference)
//
#include <hip/hip_runtime.h>
#include <math.h>

typedef _Float16 f16;
typedef f16 f16x8 __attribute__((ext_vector_type(8)));
typedef f16 f16x4 __attribute__((ext_vector_type(4)));
typedef float f32x4 __attribute__((ext_vector_type(4)));
typedef unsigned int u32;
typedef unsigned long long u64;

#define TT 64
#define DD 768
#define MR 1024      // B*T = 16*64
#define ALPHAF 0.4f
#define NWG 120      // persistent scan workgroups
#define LMN 50257
#define LMK 768

__device__ __forceinline__ float geluf(float x){
  return 0.5f*x*(1.0f + erff(x*0.70710678118654752f));
}

// ---- coherent (agent-scope, LLC) activation accessors ----
__device__ __forceinline__ u64 ld_a64(const void* p){
  return __hip_atomic_load((const u64*)p, __ATOMIC_RELAXED, __HIP_MEMORY_SCOPE_AGENT);
}
__device__ __forceinline__ f16x8 ld_act16h(const f16* p){
  union { u64 u[2]; f16x8 v; } c;
  c.u[0] = ld_a64(p); c.u[1] = ld_a64(p + 4); return c.v;
}
__device__ __forceinline__ float ld_actf(const float* p){
  union { u32 u; float f; } c;
  c.u = __hip_atomic_load((const u32*)p, __ATOMIC_RELAXED, __HIP_MEMORY_SCOPE_AGENT);
  return c.f;
}
__device__ __forceinline__ void st_actf(float* p, float v){
  union { u32 u; float f; } c; c.f = v;
  __hip_atomic_store((u32*)p, c.u, __ATOMIC_RELAXED, __HIP_MEMORY_SCOPE_AGENT);
}
__device__ __forceinline__ void st_acth(f16* p, float v){
  union { unsigned short u; f16 h; } c; c.h = (f16)v;
  __hip_atomic_store((unsigned short*)p, c.u, __ATOMIC_RELAXED, __HIP_MEMORY_SCOPE_AGENT);
}

// ---------------- embedding ----------------
__global__ __launch_bounds__(256) void k_embed(const int* __restrict__ tok,
    const float* __restrict__ emb, const float* __restrict__ pos, float* __restrict__ x){
  int m = blockIdx.x; int t = m & 63; int id = tok[m];
  const float* e = emb + (size_t)id*DD;
  const float* p = pos + (size_t)t*DD;
  float* xr = x + (size_t)m*DD;
  for (int j = threadIdx.x; j < DD; j += 256) xr[j] = e[j] + p[j];
}

// ---------------- layernorm (+optional l2norm, optional [t][b][n] copy) ----------------
template<bool L2N>
__global__ __launch_bounds__(256) void k_ln(const float* __restrict__ in,
    const float* __restrict__ g, const float* __restrict__ b, float* __restrict__ out,
    float* __restrict__ outT){
  __shared__ float red[8];
  int m = blockIdx.x, tid = threadIdx.x, lane = tid & 63, wid = tid >> 6;
  const float* x = in + (size_t)m*DD;
  float v[3]; float s = 0.f, ss = 0.f;
  #pragma unroll
  for (int j = 0; j < 3; j++){ float t0 = x[tid + j*256]; v[j] = t0; s += t0; ss += t0*t0; }
  #pragma unroll
  for (int o = 1; o < 64; o <<= 1){ s += __shfl_xor(s, o); ss += __shfl_xor(ss, o); }
  if (lane == 0){ red[wid] = s; red[4+wid] = ss; }
  __syncthreads();
  s  = red[0]+red[1]+red[2]+red[3];
  ss = red[4]+red[5]+red[6]+red[7];
  float mean = s*(1.f/768.f);
  float var  = ss*(1.f/768.f) - mean*mean;
  float rstd = rsqrtf(var + 1e-5f);
  float y[3];
  #pragma unroll
  for (int j = 0; j < 3; j++){ int n = tid + j*256; y[j] = (v[j]-mean)*rstd*g[n] + b[n]; }
  if (L2N){
    float n2 = y[0]*y[0] + y[1]*y[1] + y[2]*y[2];
    #pragma unroll
    for (int o = 1; o < 64; o <<= 1) n2 += __shfl_xor(n2, o);
    __syncthreads();
    if (lane == 0) red[wid] = n2;
    __syncthreads();
    n2 = red[0]+red[1]+red[2]+red[3];
    float inv = 1.f / fmaxf(sqrtf(n2), 1e-12f);
    y[0] *= inv; y[1] *= inv; y[2] *= inv;
  }
  float* o_ = out + (size_t)m*DD;
  #pragma unroll
  for (int j = 0; j < 3; j++) o_[tid + j*256] = y[j];
  if (outT){
    float* oT = outT + ((size_t)(m & 63)*16 + (m >> 6))*DD;
    #pragma unroll
    for (int j = 0; j < 3; j++) oT[tid + j*256] = y[j];
  }
}

// ---------------- attention (one WG per (b,h)) ----------------
__global__ __launch_bounds__(256) void k_attn(const float* __restrict__ qkv, float* __restrict__ o){
  __shared__ float kv[64][96];
  __shared__ float sm[64][68];
  int bh = blockIdx.x; int b = bh >> 3, h = bh & 7;
  int tid = threadIdx.x;
  const float* base = qkv + (size_t)b*64*2304 + h*96;
  for (int idx = tid; idx < 64*96; idx += 256){ int i = idx/96, d = idx - i*96;
    kv[i][d] = base[(size_t)i*2304 + 768 + d]; }
  __syncthreads();
  {
    int i = tid >> 2;
    const float* q = base + (size_t)i*2304;
    int j0 = (tid & 3)*16;
    for (int jj = 0; jj < 16; jj++){
      int j = j0 + jj;
      float sv = -1e30f;
      if (j <= i){ float acc = 0.f;
        for (int d = 0; d < 96; d++) acc += q[d]*kv[j][d];
        sv = acc*0.10206207261596576f; }
      sm[i][j] = sv;
    }
  }
  __syncthreads();
  for (int idx = tid; idx < 64*96; idx += 256){ int i = idx/96, d = idx - i*96;
    kv[i][d] = base[(size_t)i*2304 + 1536 + d]; }
  if (tid < 64){
    int i = tid;
    float mx = -1e30f;
    for (int j = 0; j <= i; j++) mx = fmaxf(mx, sm[i][j]);
    float sum = 0.f;
    for (int j = 0; j <= i; j++){ float e = expf(sm[i][j]-mx); sm[i][j] = e; sum += e; }
    float inv = 1.f/sum;
    for (int j = 0; j <= i; j++) sm[i][j] *= inv;
  }
  __syncthreads();
  for (int idx = tid; idx < 64*96; idx += 256){
    int i = idx/96, d = idx - i*96;
    float acc = 0.f;
    for (int j = 0; j <= i; j++) acc += sm[i][j]*kv[j][d];
    o[(size_t)(b*64+i)*768 + h*96 + d] = acc;
  }
}

// -------- generic fp16 MFMA GEMM (fp32 in), XCD-chunked m-inner, optional permuted out --------
// operm: 0 -> [m][n]; 1 -> [t][b][n] (m = b*64+t); 2 -> [t][n][b]
__global__ __launch_bounds__(256) void k_gemm(
    const float* __restrict__ A, int lda,
    const float* __restrict__ Bw, int ldb, int nrb,
    int M, int N, int K, int mblocks, int operm,
    const float* __restrict__ bias, const float* __restrict__ res,
    float* __restrict__ outF, f16* __restrict__ outH,
    float scale, int act)
{
  __shared__ f16 As[128][40];
  __shared__ f16 Bs[128][40];
  int tid = threadIdx.x;
  int nb = gridDim.x;
  int q = nb >> 3, rm = nb & 7, xcd = blockIdx.x & 7;
  int base0 = (xcd < rm) ? xcd*(q+1) : rm*(q+1) + (xcd - rm)*q;
  int orig = base0 + (blockIdx.x >> 3);
  int m0 = (orig % mblocks)*128, n0 = (orig / mblocks)*128;
  int lane = tid & 63, wid = tid >> 6;
  int wr = (wid >> 1)*64, wc = (wid & 1)*64;
  int l15 = lane & 15, kb = lane >> 4;
  f32x4 acc[4][4];
  #pragma unroll
  for (int i = 0; i < 4; i++)
    #pragma unroll
    for (int j = 0; j < 4; j++){ f32x4 z = {0.f,0.f,0.f,0.f}; acc[i][j] = z; }
  int rA = tid >> 3;          // 0..31
  int k4 = (tid & 7)*4;       // 0..28
  for (int kk = 0; kk < K; kk += 32){
    #pragma unroll
    for (int it = 0; it < 4; ++it){
      int r = it*32 + rA;
      float4 va = *(const float4*)(A + (size_t)(m0+r)*lda + kk + k4);
      *(f16x4*)(&As[r][k4]) = (f16x4){(f16)va.x,(f16)va.y,(f16)va.z,(f16)va.w};
      int rB = n0 + r;
      float4 vb;
      if (rB < nrb) vb = *(const float4*)(Bw + (size_t)rB*ldb + kk + k4);
      else { vb.x = 0.f; vb.y = 0.f; vb.z = 0.f; vb.w = 0.f; }
      *(f16x4*)(&Bs[r][k4]) = (f16x4){(f16)vb.x,(f16)vb.y,(f16)vb.z,(f16)vb.w};
    }
    __syncthreads();
    f16x8 af[4], bfv[4];
    #pragma unroll
    for (int i = 0; i < 4; i++) af[i]  = *(const f16x8*)(&As[wr + i*16 + l15][kb*8]);
    #pragma unroll
    for (int j = 0; j < 4; j++) bfv[j] = *(const f16x8*)(&Bs[wc + j*16 + l15][kb*8]);
    #pragma unroll
    for (int i = 0; i < 4; i++)
      #pragma unroll
      for (int j = 0; j < 4; j++)
        acc[i][j] = __builtin_amdgcn_mfma_f32_16x16x32_f16(af[i], bfv[j], acc[i][j], 0, 0, 0);
    __syncthreads();
  }
  #pragma unroll
  for (int i = 0; i < 4; i++){
    #pragma unroll
    for (int j = 0; j < 4; j++){
      #pragma unroll
      for (int r = 0; r < 4; r++){
        int m = m0 + wr + i*16 + kb*4 + r;
        int n = n0 + wc + j*16 + l15;
        if (n < N){
          float v = acc[i][j][r]*scale;
          if (bias) v += bias[n];
          if (act == 1) v = geluf(v);
          if (res) v += res[(size_t)m*N + n];
          size_t off;
          if (operm == 0)      off = (size_t)m*N + n;
          else if (operm == 1) off = ((size_t)(m & 63)*16 + (m >> 6))*N + n;
          else                 off = ((size_t)(m & 63)*N + n)*16 + (m >> 6);
          if (outF) outF[off] = v;
          if (outH) outH[off] = (f16)v;
        }
      }
    }
  }
}

// -------- lm-head: no-LDS direct-fragment GEMM, A f16 (L2-resident), B fp32 streamed --------
__global__ __launch_bounds__(256) void k_lmhead(
    const f16* __restrict__ A, const float* __restrict__ Bw, float* __restrict__ outF)
{
  int tid = threadIdx.x;
  int nb = gridDim.x;
  int q = nb >> 3, rm = nb & 7, xcd = blockIdx.x & 7;
  int base0 = (xcd < rm) ? xcd*(q+1) : rm*(q+1) + (xcd - rm)*q;
  int orig = base0 + (blockIdx.x >> 3);
  int m0 = (orig & 7)*128, n0 = (orig >> 3)*128;   // m-inner: 8 consecutive blocks share B panel
  int lane = tid & 63, wid = tid >> 6;
  int wr = (wid >> 1)*64, wc = (wid & 1)*64;
  int l15 = lane & 15, kb = lane >> 4;
  f32x4 acc[4][4];
  #pragma unroll
  for (int i = 0; i < 4; i++)
    #pragma unroll
    for (int j = 0; j < 4; j++){ f32x4 z = {0.f,0.f,0.f,0.f}; acc[i][j] = z; }
  const f16* Ap = A + (size_t)(m0 + wr + l15)*LMK + kb*8;
  const float* Bp[4];
  #pragma unroll
  for (int j = 0; j < 4; j++){
    int r = n0 + wc + j*16 + l15;
    if (r > LMN-1) r = LMN-1;            // clamp; epilogue guard discards
    Bp[j] = Bw + (size_t)r*LMK + kb*8;
  }
  #pragma unroll 4
  for (int kk = 0; kk < LMK; kk += 32){
    f16x8 af[4], bfv[4];
    #pragma unroll
    for (int i = 0; i < 4; i++) af[i] = *(const f16x8*)(Ap + (size_t)i*16*LMK + kk);
    #pragma unroll
    for (int j = 0; j < 4; j++){
      float4 b0 = *(const float4*)(Bp[j] + kk);
      float4 b1 = *(const float4*)(Bp[j] + kk + 4);
      bfv[j] = (f16x8){(f16)b0.x,(f16)b0.y,(f16)b0.z,(f16)b0.w,
                       (f16)b1.x,(f16)b1.y,(f16)b1.z,(f16)b1.w};
    }
    #pragma unroll
    for (int i = 0; i < 4; i++)
      #pragma unroll
      for (int j = 0; j < 4; j++)
        acc[i][j] = __builtin_amdgcn_mfma_f32_16x16x32_f16(af[i], bfv[j], acc[i][j], 0, 0, 0);
  }
  #pragma unroll
  for (int i = 0; i < 4; i++){
    #pragma unroll
    for (int j = 0; j < 4; j++){
      #pragma unroll
      for (int r = 0; r < 4; r++){
        int m = m0 + wr + i*16 + kb*4 + r;
        int n = n0 + wc + j*16 + l15;
        if (n < LMN) outF[(size_t)m*LMN + n] = acc[i][j][r];
      }
    }
  }
}

// ---------------- transpose / cast helpers ----------------
__global__ __launch_bounds__(256) void k_transpose_f(const float* __restrict__ in, float* __restrict__ out, int R, int C){
  __shared__ float tile[32][33];
  int r0 = blockIdx.y*32, c0 = blockIdx.x*32;
  int tx = threadIdx.x & 31, ty = threadIdx.x >> 5;
  #pragma unroll
  for (int i = 0; i < 32; i += 8) tile[ty+i][tx] = in[(size_t)(r0+ty+i)*C + (c0+tx)];
  __syncthreads();
  #pragma unroll
  for (int i = 0; i < 32; i += 8) out[(size_t)(c0+ty+i)*R + (r0+tx)] = tile[tx][ty+i];
}

__global__ __launch_bounds__(256) void k_transpose_h(const float* __restrict__ in, f16* __restrict__ out, int R, int C){
  __shared__ float tile[32][33];
  int r0 = blockIdx.y*32, c0 = blockIdx.x*32;
  int tx = threadIdx.x & 31, ty = threadIdx.x >> 5;
  #pragma unroll
  for (int i = 0; i < 32; i += 8) tile[ty+i][tx] = in[(size_t)(r0+ty+i)*C + (c0+tx)];
  __syncthreads();
  #pragma unroll
  for (int i = 0; i < 32; i += 8) out[(size_t)(c0+ty+i)*R + (r0+tx)] = (f16)tile[tx][ty+i];
}

__global__ __launch_bounds__(256) void k_cast_h(const float* __restrict__ in, f16* __restrict__ out, int n){
  int i = blockIdx.x*256 + threadIdx.x;
  if (i < n) out[i] = (f16)in[i];
}

__global__ __launch_bounds__(256) void k_bdg(const float* __restrict__ gw, const float* __restrict__ cpb2, float* __restrict__ bdg){
  int g = blockIdx.x*256 + threadIdx.x;
  if (g < 768){
    const float* row = gw + (size_t)g*1536 + 768;
    float s = 0.f;
    for (int j = 0; j < 768; j++) s += cpb2[j]*row[j];
    bdg[g] = s;
  }
}

__global__ void k_init(int* flags){
  for (int i = threadIdx.x; i < 256*32; i += 256) flags[i] = 0;
}

// ---------------- persistent scan: fp16 weights in LDS, producer-subset flag chain ----------------
__device__ __forceinline__ void red_store(float* rb, int lane, f32x4 a){
  rb[lane] = a[0]; rb[64+lane] = a[1]; rb[128+lane] = a[2]; rb[192+lane] = a[3];
}
__device__ __forceinline__ f32x4 red_sum4(float rb[4][256], int lane){
  f32x4 s;
  #pragma unroll
  for (int r = 0; r < 4; r++)
    s[r] = rb[0][r*64+lane] + rb[1][r*64+lane] + rb[2][r*64+lane] + rb[3][r*64+lane];
  return s;
}
__device__ __forceinline__ f32x4 red_sum2(float rb[4][256], int lane, int w0, int w1){
  f32x4 s;
  #pragma unroll
  for (int r = 0; r < 4; r++)
    s[r] = rb[w0][r*64+lane] + rb[w1][r*64+lane];
  return s;
}

// post: drain this WG's stores, then publish epoch on own cacheline-strided flag
__device__ __forceinline__ void postf(int* f, int ep){
  asm volatile("s_waitcnt vmcnt(0)" ::: "memory");
  __syncthreads();
  if (threadIdx.x == 0)
    __hip_atomic_store(f, ep, __ATOMIC_RELAXED, __HIP_MEMORY_SCOPE_AGENT);
}
// wait: wave 0 polls n producer flags; other waves park at syncthreads
__device__ __forceinline__ void waitf(const int* f, int n, int ep){
  if (threadIdx.x < 64){
    int lane = threadIdx.x;
    while (true){
      bool ok = true;
      for (int i = lane; i < n; i += 64){
        if (__hip_atomic_load(f + i*32, __ATOMIC_RELAXED, __HIP_MEMORY_SCOPE_AGENT) < ep){
          ok = false; break;
        }
      }
      if (__ballot(ok) == ~0ull) break;
      __builtin_amdgcn_s_sleep(1);
    }
  }
  __syncthreads();
}

__global__ __launch_bounds__(256, 1) void k_scan(
  const f16* __restrict__ WAf, const f16* __restrict__ V1tf,
  const f16* __restrict__ Wc1f, const f16* __restrict__ WDf,
  const float* __restrict__ ctxV0T,   // [t][n3072][b16]
  const float* __restrict__ gctxT,    // [t][b16][768]
  const float* __restrict__ ctxT,     // [t][b16][768]
  const float* __restrict__ b1, const float* __restrict__ cpb1,
  const float* __restrict__ cpb2, const float* __restrict__ bdg,
  const float* __restrict__ gateb, const float* __restrict__ outg, const float* __restrict__ outb,
  f16* __restrict__ hf,
  f16* __restrict__ h1f, f16* __restrict__ c1f, f16* __restrict__ gcaf,
  float* __restrict__ cf, float* __restrict__ gpre,
  float* __restrict__ tfs, int* flags)
{
  __shared__ __align__(16) char smem[147456];
  __shared__ float redbuf[4][256];
  __shared__ float normp[4][16];
  __shared__ float red[8];
  const int tid = threadIdx.x, lane = tid & 63, wid = tid >> 6;
  const int bid = blockIdx.x;
  const int l15 = lane & 15, kb = lane >> 4;
  int* afl = flags;                 // 120
  int* bfl = flags + 120*32;        // 48
  int* cfl = flags + 168*32;        // 24
  int* dfl = flags + 192*32;        // 48
  int* mfl = flags + 240*32;        // 16

  // ---- stage weights into LDS (once) ----
  {
    const f16* src = WAf + (size_t)bid*32*768;
    for (int c = tid; c < 3072; c += 256){
      int row = c/96, kc = c - row*96;
      int off = (row*1536 + kc*16) ^ ((row&7)<<4);
      *(f16x8*)(smem + off) = *(const f16x8*)(src + (size_t)row*768 + kc*8);
    }
    if (bid < 48){
      const f16* s2 = V1tf + (size_t)bid*16*3072;
      for (int c = tid; c < 6144; c += 256){
        int row = c/384, kc = c - row*384;
        int off = (row*6144 + kc*16) ^ ((row&7)<<4);
        *(f16x8*)(smem + 49152 + off) = *(const f16x8*)(s2 + (size_t)row*3072 + kc*8);
      }
    } else if (bid < 72){
      const f16* s2 = Wc1f + (size_t)(bid-48)*32*768;
      for (int c = tid; c < 3072; c += 256){
        int row = c/96, kc = c - row*96;
        int off = (row*1536 + kc*16) ^ ((row&7)<<4);
        *(f16x8*)(smem + 49152 + off) = *(const f16x8*)(s2 + (size_t)row*768 + kc*8);
      }
    } else {
      const f16* s2 = WDf + (size_t)(bid-72)*32*768;
      for (int c = tid; c < 3072; c += 256){
        int row = c/96, kc = c - row*96;
        int off = (row*1536 + kc*16) ^ ((row&7)<<4);
        *(f16x8*)(smem + 49152 + off) = *(const f16x8*)(s2 + (size_t)row*768 + kc*8);
      }
    }
  }
  __syncthreads();

  // ---- t-invariant hoists ----
  const int n_a = bid*32 + (wid>>1)*16 + l15;
  float b1v = 0.f;
  if (bid < 48) b1v = b1[bid*16 + l15];
  float cpb1v = 0.f;
  if (bid >= 48 && bid < 72) cpb1v = cpb1[((bid-48)*2 + (wid>>1))*16 + l15];
  float dbv = 0.f; int n_d = 0;
  if (bid >= 72){
    n_d = ((bid-72)*2 + (wid>>1))*16 + l15;
    dbv = (n_d < 768) ? cpb2[n_d] : bdg[n_d - 768];
  }
  float gb3[3], og3[3], ob3[3];
  if (bid < 16){
    #pragma unroll
    for (int j = 0; j < 3; j++){
      int n = tid + j*256;
      gb3[j] = gateb[n]; og3[j] = outg[n]; ob3[j] = outb[n];
    }
  }

  for (int t = 0; t < TT; ++t){
    const int ep = t + 1;
    // ---- per-step prefetch: stage-A epilogue slice (issued before the wait) ----
    f32x4 cv = {0.f,0.f,0.f,0.f};
    if ((wid & 1) == 0 && n_a < 3072)
      cv = *(const f32x4*)(ctxV0T + ((size_t)t*3072 + n_a)*16 + kb*4);

    if (t > 0) waitf(mfl, 16, t);      // hf(t-1) published
    // ==== stage A (all 120 WGs)
    {
      const int u = wid >> 1, kh = wid & 1;
      const int k0 = kh*384 + kb*8;
      f32x4 a = {0.f,0.f,0.f,0.f};
      if (t > 0){
        const f16* ap = hf + ((size_t)l15*TT + (t-1))*DD + k0;
        const int row = u*16 + l15, rowoff = row*1536, sw = (row&7)<<4;
        #pragma unroll
        for (int b = 0; b < 12; b++){
          int wb = (rowoff + (k0 + b*32)*2) ^ sw;
          f16x8 vb = *(const f16x8*)(smem + wb);
          f16x8 va = ld_act16h(ap + b*32);
          a = __builtin_amdgcn_mfma_f32_16x16x32_f16(va, vb, a, 0,0,0);
        }
      }
      red_store(redbuf[wid], lane, a);
    }
    __syncthreads();
    if ((wid & 1) == 0){
      f32x4 s4 = red_sum2(redbuf, lane, wid, wid+1);
      #pragma unroll
      for (int r = 0; r < 4; r++){
        int m = kb*4 + r;
        if (n_a < 3072){
          float hv = geluf(s4[r] + cv[r]);
          st_acth(h1f + (size_t)m*3072 + n_a, hv);
        } else {
          st_actf(tfs + m*DD + (n_a - 3072), s4[r]);
        }
      }
    }
    postf(afl + bid*32, ep);
    // ==== stage B (bids 0..47)
    if (bid < 48){
      waitf(afl, 120, ep);
      const int k0 = wid*768 + kb*8;
      const f16* ap = h1f + (size_t)l15*3072 + k0;
      const int rowoff = l15*6144, sw = (l15&7)<<4;
      f32x4 a = {0.f,0.f,0.f,0.f};
      #pragma unroll
      for (int b = 0; b < 24; b++){
        int wb = (rowoff + (k0 + b*32)*2) ^ sw;
        f16x8 vb = *(const f16x8*)(smem + 49152 + wb);
        f16x8 va = ld_act16h(ap + b*32);
        a = __builtin_amdgcn_mfma_f32_16x16x32_f16(va, vb, a, 0,0,0);
      }
      red_store(redbuf[wid], lane, a);
      __syncthreads();
      if (wid == 0){
        f32x4 s4 = red_sum4(redbuf, lane);
        int n = bid*16 + l15;
        #pragma unroll
        for (int r = 0; r < 4; r++){
          int m = kb*4 + r;
          st_acth(c1f + (size_t)m*DD + n, geluf(s4[r] + b1v));
        }
      }
      postf(bfl + bid*32, ep);
    }
    // ---- combine-slice prefetch (bids 0..15) ----
    float gv[3], cxv[3];
    if (bid < 16){
      #pragma unroll
      for (int j = 0; j < 3; j++){
        size_t o = ((size_t)t*16 + bid)*DD + tid + j*256;
        gv[j] = gctxT[o]; cxv[j] = ctxT[o];
      }
    }
    // ==== stage C (bids 48..71)
    if (bid >= 48 && bid < 72){
      waitf(bfl, 48, ep);
      const int u = wid >> 1, kh = wid & 1;
      const int k0 = kh*384 + kb*8;
      const f16* ap = c1f + (size_t)l15*DD + k0;
      const int row = u*16 + l15, rowoff = row*1536, sw = (row&7)<<4;
      f32x4 a = {0.f,0.f,0.f,0.f};
      float sq = 0.f;
      #pragma unroll
      for (int b = 0; b < 12; b++){
        int wb = (rowoff + (k0 + b*32)*2) ^ sw;
        f16x8 vb = *(const f16x8*)(smem + 49152 + wb);
        f16x8 va = ld_act16h(ap + b*32);
        a = __builtin_amdgcn_mfma_f32_16x16x32_f16(va, vb, a, 0,0,0);
        #pragma unroll
        for (int j = 0; j < 8; j++){ float xv = (float)va[j]; sq = fmaf(xv, xv, sq); }
      }
      sq += __shfl_xor(sq,16); sq += __shfl_xor(sq,32);
      if (lane < 16) normp[wid][lane] = sq;
      red_store(redbuf[wid], lane, a);
      __syncthreads();
      if ((wid & 1) == 0){
        f32x4 s4 = red_sum2(redbuf, lane, wid, wid+1);
        int n = ((bid-48)*2 + (wid>>1))*16 + l15;
        #pragma unroll
        for (int r = 0; r < 4; r++){
          int m = kb*4 + r;
          float nm = normp[wid][m] + normp[wid+1][m];
          float inv = 1.f / fmaxf(sqrtf(nm), 1e-12f);
          st_acth(gcaf + (size_t)m*DD + n, geluf(s4[r]*inv + cpb1v));
        }
      }
      postf(cfl + (bid-48)*32, ep);
    }
    // ==== stage D (bids 72..119)
    if (bid >= 72){
      waitf(cfl, 24, ep);
      const int u = wid >> 1, kh = wid & 1;
      const int k0 = kh*384 + kb*8;
      const f16* ap = gcaf + (size_t)l15*DD + k0;
      const int row = u*16 + l15, rowoff = row*1536, sw = (row&7)<<4;
      f32x4 a = {0.f,0.f,0.f,0.f};
      #pragma unroll
      for (int b = 0; b < 12; b++){
        int wb = (rowoff + (k0 + b*32)*2) ^ sw;
        f16x8 vb = *(const f16x8*)(smem + 49152 + wb);
        f16x8 va = ld_act16h(ap + b*32);
        a = __builtin_amdgcn_mfma_f32_16x16x32_f16(va, vb, a, 0,0,0);
      }
      red_store(redbuf[wid], lane, a);
      __syncthreads();
      if ((wid & 1) == 0){
        f32x4 s4 = red_sum2(redbuf, lane, wid, wid+1);
        #pragma unroll
        for (int r = 0; r < 4; r++){
          int m = kb*4 + r;
          if (n_d < 768) st_actf(cf + m*DD + n_d, s4[r] + dbv);
          else           st_actf(gpre + m*DD + (n_d - 768), s4[r] + dbv);
        }
      }
      postf(dfl + (bid-72)*32, ep);
    }
    // ==== combine (bids 0..15)
    if (bid < 16){
      waitf(dfl, 48, ep);
      int m = bid;
      float vals[3]; float s = 0.f, ss = 0.f;
      #pragma unroll
      for (int j = 0; j < 3; j++){
        int n = tid + j*256;
        float gi = gv[j] + ld_actf(gpre + m*DD + n) + gb3[j];
        float gate = 1.f/(1.f + expf(-gi));
        float v = gate*(ld_actf(cf + m*DD + n) + ld_actf(tfs + m*DD + n)) + (1.f - gate)*cxv[j];
        vals[j] = v; s += v; ss += v*v;
      }
      #pragma unroll
      for (int o = 1; o < 64; o <<= 1){ s += __shfl_xor(s, o); ss += __shfl_xor(ss, o); }
      if (lane == 0){ red[wid] = s; red[4+wid] = ss; }
      __syncthreads();
      s  = red[0]+red[1]+red[2]+red[3];
      ss = red[4]+red[5]+red[6]+red[7];
      float mean = s*(1.f/768.f), var = ss*(1.f/768.f) - mean*mean;
      float rstd = rsqrtf(var + 1e-5f);
      #pragma unroll
      for (int j = 0; j < 3; j++){
        int n = tid + j*256;
        float y = (vals[j]-mean)*rstd*og3[j] + ob3[j];
        y = fminf(5.f, fmaxf(-5.f, y));
        st_acth(hf + ((size_t)m*TT + t)*DD + n, y);
      }
      postf(mfl + bid*32, ep);
    }
  }
}

// ---------------- host ----------------
static inline void gemmH(hipStream_t s, const float* A, int lda, const float* Bw, int ldb, int nrb,
                        int M, int N, int K, int operm, const float* bias, const float* res,
                        float* outF, f16* outH, float scale, int act){
  int my = M/128, nx = (N + 127)/128;
  k_gemm<<<nx*my, 256, 0, s>>>(A, lda, Bw, ldb, nrb, M, N, K, my, operm, bias, res, outF, outH, scale, act);
}

extern "C" void kernel_launch(void* const* d_in, const int* in_sizes, int n_in,
                              void* d_out, int out_size, void* d_ws, size_t ws_size,
                              hipStream_t stream)
{
  (void)in_sizes; (void)n_in; (void)out_size; (void)ws_size;
  const int*   tok = (const int*)d_in[0];
  const float* emb = (const float*)d_in[1];
  const float* pos = (const float*)d_in[2];
  const float* aiw = (const float*)d_in[3];
  const float* aib = (const float*)d_in[4];
  const float* aow = (const float*)d_in[5];
  const float* aob = (const float*)d_in[6];
  const float* fw1 = (const float*)d_in[7];
  const float* fb1 = (const float*)d_in[8];
  const float* fw2 = (const float*)d_in[9];
  const float* fb2 = (const float*)d_in[10];
  const float* n1g = (const float*)d_in[11];
  const float* n1b = (const float*)d_in[12];
  const float* n2g = (const float*)d_in[13];
  const float* n2b = (const float*)d_in[14];
  const float* eng = (const float*)d_in[15];
  const float* enb = (const float*)d_in[16];
  const float* V0  = (const float*)d_in[17];
  const float* b0  = (const float*)d_in[18];
  const float* V1  = (const float*)d_in[19];
  const float* b1  = (const float*)d_in[20];
  const float* cw1 = (const float*)d_in[21];
  const float* cb1 = (const float*)d_in[22];
  const float* cw2 = (const float*)d_in[23];
  const float* cb2 = (const float*)d_in[24];
  const float* gw  = (const float*)d_in[25];
  const float* gb  = (const float*)d_in[26];
  const float* tw  = (const float*)d_in[27];
  const float* Rm  = (const float*)d_in[28];
  const float* og  = (const float*)d_in[29];
  const float* ob  = (const float*)d_in[30];
  const float* lmw = (const float*)d_in[31];
  float* out = (float*)d_out;

  char* base = (char*)d_ws; size_t off = 0;
  auto alloc = [&](size_t bytes)->void*{
    off = (off + 255) & ~(size_t)255; void* p = base + off; off += bytes; return p; };

  float* x     = (float*)alloc((size_t)MR*DD*4);
  float* xn    = (float*)alloc((size_t)MR*DD*4);
  float* qkv   = (float*)alloc((size_t)MR*2304*4);
  float* o_    = (float*)alloc((size_t)MR*DD*4);
  float* mid   = (float*)alloc((size_t)MR*2048*4);
  float* ctx   = (float*)alloc((size_t)MR*DD*4);
  float* ctxT  = (float*)alloc((size_t)MR*DD*4);
  float* V0t   = (float*)alloc((size_t)3072*768*4);
  float* cw2t  = (float*)alloc((size_t)768*768*4);
  float* ctxV0T= (float*)alloc((size_t)MR*3072*4);
  float* gctxT = (float*)alloc((size_t)MR*DD*4);
  float* bdg   = (float*)alloc(768*4);
  f16*   WAf   = (f16*)alloc((size_t)3840*768*2);
  f16*   V1tf  = (f16*)alloc((size_t)768*3072*2);
  f16*   Wc1f  = (f16*)alloc((size_t)768*768*2);
  f16*   WDf   = (f16*)alloc((size_t)1536*768*2);
  f16*   hf    = (f16*)alloc((size_t)MR*DD*2);
  f16*   h1f   = (f16*)alloc((size_t)16*3072*2);
  f16*   c1f   = (f16*)alloc((size_t)16*768*2);
  f16*   gcaf  = (f16*)alloc((size_t)16*768*2);
  float* cf    = (float*)alloc((size_t)16*768*4);
  float* gpre  = (float*)alloc((size_t)16*768*4);
  float* tfs   = (float*)alloc((size_t)16*768*4);
  int*   flags = (int*)alloc((size_t)256*32*4);

  // ----- encoder -----
  k_embed<<<MR, 256, 0, stream>>>(tok, emb, pos, x);
  for (int l = 0; l < 2; l++){
    k_ln<false><<<MR, 256, 0, stream>>>(x, n1g + l*768, n1b + l*768, xn, nullptr);
    gemmH(stream, xn, 768, aiw + (size_t)l*2304*768, 768, 2304, MR, 2304, 768, 0,
         aib + l*2304, nullptr, qkv, nullptr, 1.f, 0);
    k_attn<<<128, 256, 0, stream>>>(qkv, o_);
    gemmH(stream, o_, 768, aow + (size_t)l*768*768, 768, 768, MR, 768, 768, 0,
         aob + l*768, x, x, nullptr, 1.f, 0);
    k_ln<false><<<MR, 256, 0, stream>>>(x, n2g + l*768, n2b + l*768, xn, nullptr);
    gemmH(stream, xn, 768, fw1 + (size_t)l*2048*768, 768, 2048, MR, 2048, 768, 0,
         fb1 + l*2048, nullptr, mid, nullptr, 1.f, 1);
    gemmH(stream, mid, 2048, fw2 + (size_t)l*768*2048, 2048, 768, MR, 768, 2048, 0,
         fb2 + l*768, x, x, nullptr, 1.f, 0);
  }
  k_ln<true><<<MR, 256, 0, stream>>>(x, eng, enb, ctx, ctxT);

  // ----- precompute -----
  k_transpose_f<<<dim3(3072/32, 768/32), 256, 0, stream>>>(V0, V0t, 768, 3072);
  k_transpose_f<<<dim3(768/32, 768/32), 256, 0, stream>>>(cw2, cw2t, 768, 768);
  k_transpose_h<<<dim3(768/32, 3072/32), 256, 0, stream>>>(V1, V1tf, 3072, 768);
  k_cast_h<<<(768*768 + 255)/256, 256, 0, stream>>>(cw1, Wc1f, 768*768);
  k_cast_h<<<(768*768 + 255)/256, 256, 0, stream>>>(cw2, WDf, 768*768);
  k_bdg<<<3, 256, 0, stream>>>(gw, cb2, bdg);
  gemmH(stream, V0t, 768, Rm, 768, 768, 3072, 768, 768, 0, nullptr, nullptr,
       nullptr, WAf, ALPHAF, 0);
  gemmH(stream, tw, 768, Rm, 768, 768, 768, 768, 768, 0, nullptr, nullptr,
       nullptr, WAf + (size_t)3072*768, ALPHAF, 0);
  // ctxV0T[t][n][b] = (ctx@V0 + b0)
  gemmH(stream, ctx, 768, V0t, 768, 3072, MR, 3072, 768, 2, b0, nullptr,
       ctxV0T, nullptr, 1.f, 0);
  // gctxT[t][b][n] = ctx @ gate_w[:, :768]^T
  gemmH(stream, ctx, 768, gw, 1536, 768, MR, 768, 768, 1, nullptr, nullptr,
       gctxT, nullptr, 1.f, 0);
  gemmH(stream, gw + 768, 1536, cw2t, 768, 768, 768, 768, 768, 0, nullptr, nullptr,
       nullptr, WDf + (size_t)768*768, 1.f, 0);

  // ----- recurrence -----
  k_init<<<1, 256, 0, stream>>>(flags);
  k_scan<<<NWG, 256, 0, stream>>>(WAf, V1tf, Wc1f, WDf,
      ctxV0T, gctxT, ctxT, b1, cb1, cb2, bdg, gb, og, ob,
      hf, h1f, c1f, gcaf, cf, gpre, tfs, flags);

  // ----- lm head (f16 A from scan, fp32 B direct, no LDS) -----
  k_lmhead<<<((LMN + 127)/128)*(MR/128), 256, 0, stream>>>(hf, lmw, out);
}

// Round 11
// 3505.807 us; speedup vs baseline: 1.0732x; 1.0732x over previous
//
#include <hip/hip_runtime.h>
#include <math.h>

typedef _Float16 f16;
typedef f16 f16x8 __attribute__((ext_vector_type(8)));
typedef f16 f16x4 __attribute__((ext_vector_type(4)));
typedef float f32x4 __attribute__((ext_vector_type(4)));
typedef unsigned int u32;
typedef unsigned long long u64;

#define TT 64
#define DD 768
#define MR 1024      // B*T = 16*64
#define ALPHAF 0.4f
#define NWG 120      // scan workgroups (bids 0..119); total grid = 240 with lm-head consumers
#define LMN 50257
#define LMK 768

__device__ __forceinline__ float geluf(float x){
  return 0.5f*x*(1.0f + erff(x*0.70710678118654752f));
}

// ---- coherent (agent-scope, LLC) activation accessors ----
__device__ __forceinline__ u64 ld_a64(const void* p){
  return __hip_atomic_load((const u64*)p, __ATOMIC_RELAXED, __HIP_MEMORY_SCOPE_AGENT);
}
__device__ __forceinline__ f16x8 ld_act16h(const f16* p){
  union { u64 u[2]; f16x8 v; } c;
  c.u[0] = ld_a64(p); c.u[1] = ld_a64(p + 4); return c.v;
}
__device__ __forceinline__ float ld_actf(const float* p){
  union { u32 u; float f; } c;
  c.u = __hip_atomic_load((const u32*)p, __ATOMIC_RELAXED, __HIP_MEMORY_SCOPE_AGENT);
  return c.f;
}
__device__ __forceinline__ void st_actf(float* p, float v){
  union { u32 u; float f; } c; c.f = v;
  __hip_atomic_store((u32*)p, c.u, __ATOMIC_RELAXED, __HIP_MEMORY_SCOPE_AGENT);
}
__device__ __forceinline__ void st_acth(f16* p, float v){
  union { unsigned short u; f16 h; } c; c.h = (f16)v;
  __hip_atomic_store((unsigned short*)p, c.u, __ATOMIC_RELAXED, __HIP_MEMORY_SCOPE_AGENT);
}

// ---------------- embedding ----------------
__global__ __launch_bounds__(256) void k_embed(const int* __restrict__ tok,
    const float* __restrict__ emb, const float* __restrict__ pos, float* __restrict__ x){
  int m = blockIdx.x; int t = m & 63; int id = tok[m];
  const float* e = emb + (size_t)id*DD;
  const float* p = pos + (size_t)t*DD;
  float* xr = x + (size_t)m*DD;
  for (int j = threadIdx.x; j < DD; j += 256) xr[j] = e[j] + p[j];
}

// ---------------- layernorm (+optional l2norm, optional [t][b][n] copy) ----------------
template<bool L2N>
__global__ __launch_bounds__(256) void k_ln(const float* __restrict__ in,
    const float* __restrict__ g, const float* __restrict__ b, float* __restrict__ out,
    float* __restrict__ outT){
  __shared__ float red[8];
  int m = blockIdx.x, tid = threadIdx.x, lane = tid & 63, wid = tid >> 6;
  const float* x = in + (size_t)m*DD;
  float v[3]; float s = 0.f, ss = 0.f;
  #pragma unroll
  for (int j = 0; j < 3; j++){ float t0 = x[tid + j*256]; v[j] = t0; s += t0; ss += t0*t0; }
  #pragma unroll
  for (int o = 1; o < 64; o <<= 1){ s += __shfl_xor(s, o); ss += __shfl_xor(ss, o); }
  if (lane == 0){ red[wid] = s; red[4+wid] = ss; }
  __syncthreads();
  s  = red[0]+red[1]+red[2]+red[3];
  ss = red[4]+red[5]+red[6]+red[7];
  float mean = s*(1.f/768.f);
  float var  = ss*(1.f/768.f) - mean*mean;
  float rstd = rsqrtf(var + 1e-5f);
  float y[3];
  #pragma unroll
  for (int j = 0; j < 3; j++){ int n = tid + j*256; y[j] = (v[j]-mean)*rstd*g[n] + b[n]; }
  if (L2N){
    float n2 = y[0]*y[0] + y[1]*y[1] + y[2]*y[2];
    #pragma unroll
    for (int o = 1; o < 64; o <<= 1) n2 += __shfl_xor(n2, o);
    __syncthreads();
    if (lane == 0) red[wid] = n2;
    __syncthreads();
    n2 = red[0]+red[1]+red[2]+red[3];
    float inv = 1.f / fmaxf(sqrtf(n2), 1e-12f);
    y[0] *= inv; y[1] *= inv; y[2] *= inv;
  }
  float* o_ = out + (size_t)m*DD;
  #pragma unroll
  for (int j = 0; j < 3; j++) o_[tid + j*256] = y[j];
  if (outT){
    float* oT = outT + ((size_t)(m & 63)*16 + (m >> 6))*DD;
    #pragma unroll
    for (int j = 0; j < 3; j++) oT[tid + j*256] = y[j];
  }
}

// ---------------- attention (one WG per (b,h)) ----------------
__global__ __launch_bounds__(256) void k_attn(const float* __restrict__ qkv, float* __restrict__ o){
  __shared__ float kv[64][96];
  __shared__ float sm[64][68];
  int bh = blockIdx.x; int b = bh >> 3, h = bh & 7;
  int tid = threadIdx.x;
  const float* base = qkv + (size_t)b*64*2304 + h*96;
  for (int idx = tid; idx < 64*96; idx += 256){ int i = idx/96, d = idx - i*96;
    kv[i][d] = base[(size_t)i*2304 + 768 + d]; }
  __syncthreads();
  {
    int i = tid >> 2;
    const float* q = base + (size_t)i*2304;
    int j0 = (tid & 3)*16;
    for (int jj = 0; jj < 16; jj++){
      int j = j0 + jj;
      float sv = -1e30f;
      if (j <= i){ float acc = 0.f;
        for (int d = 0; d < 96; d++) acc += q[d]*kv[j][d];
        sv = acc*0.10206207261596576f; }
      sm[i][j] = sv;
    }
  }
  __syncthreads();
  for (int idx = tid; idx < 64*96; idx += 256){ int i = idx/96, d = idx - i*96;
    kv[i][d] = base[(size_t)i*2304 + 1536 + d]; }
  if (tid < 64){
    int i = tid;
    float mx = -1e30f;
    for (int j = 0; j <= i; j++) mx = fmaxf(mx, sm[i][j]);
    float sum = 0.f;
    for (int j = 0; j <= i; j++){ float e = expf(sm[i][j]-mx); sm[i][j] = e; sum += e; }
    float inv = 1.f/sum;
    for (int j = 0; j <= i; j++) sm[i][j] *= inv;
  }
  __syncthreads();
  for (int idx = tid; idx < 64*96; idx += 256){
    int i = idx/96, d = idx - i*96;
    float acc = 0.f;
    for (int j = 0; j <= i; j++) acc += sm[i][j]*kv[j][d];
    o[(size_t)(b*64+i)*768 + h*96 + d] = acc;
  }
}

// -------- generic fp16 MFMA GEMM (fp32 in), XCD-chunked m-inner, optional permuted out --------
// operm: 0 -> [m][n]; 1 -> [t][b][n] (m = b*64+t)
__global__ __launch_bounds__(256) void k_gemm(
    const float* __restrict__ A, int lda,
    const float* __restrict__ Bw, int ldb, int nrb,
    int M, int N, int K, int mblocks, int operm,
    const float* __restrict__ bias, const float* __restrict__ res,
    float* __restrict__ outF, f16* __restrict__ outH,
    float scale, int act)
{
  __shared__ f16 As[128][40];
  __shared__ f16 Bs[128][40];
  int tid = threadIdx.x;
  int nb = gridDim.x;
  int q = nb >> 3, rm = nb & 7, xcd = blockIdx.x & 7;
  int base0 = (xcd < rm) ? xcd*(q+1) : rm*(q+1) + (xcd - rm)*q;
  int orig = base0 + (blockIdx.x >> 3);
  int m0 = (orig % mblocks)*128, n0 = (orig / mblocks)*128;
  int lane = tid & 63, wid = tid >> 6;
  int wr = (wid >> 1)*64, wc = (wid & 1)*64;
  int l15 = lane & 15, kb = lane >> 4;
  f32x4 acc[4][4];
  #pragma unroll
  for (int i = 0; i < 4; i++)
    #pragma unroll
    for (int j = 0; j < 4; j++){ f32x4 z = {0.f,0.f,0.f,0.f}; acc[i][j] = z; }
  int rA = tid >> 3;          // 0..31
  int k4 = (tid & 7)*4;       // 0..28
  for (int kk = 0; kk < K; kk += 32){
    #pragma unroll
    for (int it = 0; it < 4; ++it){
      int r = it*32 + rA;
      float4 va = *(const float4*)(A + (size_t)(m0+r)*lda + kk + k4);
      *(f16x4*)(&As[r][k4]) = (f16x4){(f16)va.x,(f16)va.y,(f16)va.z,(f16)va.w};
      int rB = n0 + r;
      float4 vb;
      if (rB < nrb) vb = *(const float4*)(Bw + (size_t)rB*ldb + kk + k4);
      else { vb.x = 0.f; vb.y = 0.f; vb.z = 0.f; vb.w = 0.f; }
      *(f16x4*)(&Bs[r][k4]) = (f16x4){(f16)vb.x,(f16)vb.y,(f16)vb.z,(f16)vb.w};
    }
    __syncthreads();
    f16x8 af[4], bfv[4];
    #pragma unroll
    for (int i = 0; i < 4; i++) af[i]  = *(const f16x8*)(&As[wr + i*16 + l15][kb*8]);
    #pragma unroll
    for (int j = 0; j < 4; j++) bfv[j] = *(const f16x8*)(&Bs[wc + j*16 + l15][kb*8]);
    #pragma unroll
    for (int i = 0; i < 4; i++)
      #pragma unroll
      for (int j = 0; j < 4; j++)
        acc[i][j] = __builtin_amdgcn_mfma_f32_16x16x32_f16(af[i], bfv[j], acc[i][j], 0, 0, 0);
    __syncthreads();
  }
  #pragma unroll
  for (int i = 0; i < 4; i++){
    #pragma unroll
    for (int j = 0; j < 4; j++){
      #pragma unroll
      for (int r = 0; r < 4; r++){
        int m = m0 + wr + i*16 + kb*4 + r;
        int n = n0 + wc + j*16 + l15;
        if (n < N){
          float v = acc[i][j][r]*scale;
          if (bias) v += bias[n];
          if (act == 1) v = geluf(v);
          if (res) v += res[(size_t)m*N + n];
          size_t off;
          if (operm == 0) off = (size_t)m*N + n;
          else            off = ((size_t)(m & 63)*16 + (m >> 6))*N + n;
          if (outF) outF[off] = v;
          if (outH) outH[off] = (f16)v;
        }
      }
    }
  }
}

// ---------------- transpose / cast helpers ----------------
__global__ __launch_bounds__(256) void k_transpose_f(const float* __restrict__ in, float* __restrict__ out, int R, int C){
  __shared__ float tile[32][33];
  int r0 = blockIdx.y*32, c0 = blockIdx.x*32;
  int tx = threadIdx.x & 31, ty = threadIdx.x >> 5;
  #pragma unroll
  for (int i = 0; i < 32; i += 8) tile[ty+i][tx] = in[(size_t)(r0+ty+i)*C + (c0+tx)];
  __syncthreads();
  #pragma unroll
  for (int i = 0; i < 32; i += 8) out[(size_t)(c0+ty+i)*R + (r0+tx)] = tile[tx][ty+i];
}

__global__ __launch_bounds__(256) void k_transpose_h(const float* __restrict__ in, f16* __restrict__ out, int R, int C){
  __shared__ float tile[32][33];
  int r0 = blockIdx.y*32, c0 = blockIdx.x*32;
  int tx = threadIdx.x & 31, ty = threadIdx.x >> 5;
  #pragma unroll
  for (int i = 0; i < 32; i += 8) tile[ty+i][tx] = in[(size_t)(r0+ty+i)*C + (c0+tx)];
  __syncthreads();
  #pragma unroll
  for (int i = 0; i < 32; i += 8) out[(size_t)(c0+ty+i)*R + (r0+tx)] = (f16)tile[tx][ty+i];
}

__global__ __launch_bounds__(256) void k_cast_h(const float* __restrict__ in, f16* __restrict__ out, int n){
  int i = blockIdx.x*256 + threadIdx.x;
  if (i < n) out[i] = (f16)in[i];
}

// vectorized cast: 8 floats -> 8 f16 per thread
__global__ __launch_bounds__(256) void k_cast_h8(const float* __restrict__ in, f16* __restrict__ out, int n8){
  int i = blockIdx.x*256 + threadIdx.x;
  if (i < n8){
    float4 a = ((const float4*)in)[i*2];
    float4 b = ((const float4*)in)[i*2 + 1];
    ((f16x8*)out)[i] = (f16x8){(f16)a.x,(f16)a.y,(f16)a.z,(f16)a.w,
                               (f16)b.x,(f16)b.y,(f16)b.z,(f16)b.w};
  }
}

__global__ __launch_bounds__(256) void k_bdg(const float* __restrict__ gw, const float* __restrict__ cpb2, float* __restrict__ bdg){
  int g = blockIdx.x*256 + threadIdx.x;
  if (g < 768){
    const float* row = gw + (size_t)g*1536 + 768;
    float s = 0.f;
    for (int j = 0; j < 768; j++) s += cpb2[j]*row[j];
    bdg[g] = s;
  }
}

__global__ void k_init(int* flags){
  for (int i = threadIdx.x; i < 256*32; i += 256) flags[i] = 0;
}

// ---------------- persistent scan + fused lm-head consumers ----------------
__device__ __forceinline__ void red_store(float* rb, int lane, f32x4 a){
  rb[lane] = a[0]; rb[64+lane] = a[1]; rb[128+lane] = a[2]; rb[192+lane] = a[3];
}
__device__ __forceinline__ f32x4 red_sum4(float rb[4][256], int lane){
  f32x4 s;
  #pragma unroll
  for (int r = 0; r < 4; r++)
    s[r] = rb[0][r*64+lane] + rb[1][r*64+lane] + rb[2][r*64+lane] + rb[3][r*64+lane];
  return s;
}
__device__ __forceinline__ f32x4 red_sum2(float rb[4][256], int lane, int w0, int w1){
  f32x4 s;
  #pragma unroll
  for (int r = 0; r < 4; r++)
    s[r] = rb[w0][r*64+lane] + rb[w1][r*64+lane];
  return s;
}

__device__ __forceinline__ void postf(int* f, int ep){
  asm volatile("s_waitcnt vmcnt(0)" ::: "memory");
  __syncthreads();
  if (threadIdx.x == 0)
    __hip_atomic_store(f, ep, __ATOMIC_RELAXED, __HIP_MEMORY_SCOPE_AGENT);
}
__device__ __forceinline__ void waitf(const int* f, int n, int ep){
  if (threadIdx.x < 64){
    int lane = threadIdx.x;
    while (true){
      bool ok = true;
      for (int i = lane; i < n; i += 64){
        if (__hip_atomic_load(f + i*32, __ATOMIC_RELAXED, __HIP_MEMORY_SCOPE_AGENT) < ep){
          ok = false; break;
        }
      }
      if (__ballot(ok) == ~0ull) break;
      __builtin_amdgcn_s_sleep(1);
    }
  }
  __syncthreads();
}

__global__ __launch_bounds__(256, 1) void k_scan(
  const f16* __restrict__ WAf, const f16* __restrict__ V1tf,
  const f16* __restrict__ Wc1f, const f16* __restrict__ WDf,
  const float* __restrict__ ctxV0T,   // [t][b16][3072]
  const float* __restrict__ gctxT,    // [t][b16][768]
  const float* __restrict__ ctxT,     // [t][b16][768]
  const float* __restrict__ b1, const float* __restrict__ cpb1,
  const float* __restrict__ cpb2, const float* __restrict__ bdg,
  const float* __restrict__ gateb, const float* __restrict__ outg, const float* __restrict__ outb,
  f16* __restrict__ hf,
  f16* __restrict__ h1f, f16* __restrict__ c1f, f16* __restrict__ gcaf,
  float* __restrict__ cf, float* __restrict__ gpre,
  float* __restrict__ tfs, int* flags,
  const f16* __restrict__ lmw16, float* __restrict__ out)
{
  __shared__ __align__(16) char smem[147456];
  __shared__ float redbuf[4][256];
  __shared__ float normp[4][16];
  __shared__ float red[8];
  const int tid = threadIdx.x, lane = tid & 63, wid = tid >> 6;
  const int bid = blockIdx.x;
  const int l15 = lane & 15, kb = lane >> 4;
  int* afl = flags;                 // 120
  int* bfl = flags + 120*32;        // 48
  int* cfl = flags + 168*32;        // 24
  int* dfl = flags + 192*32;        // 48
  int* mfl = flags + 240*32;        // 16

  if (bid >= NWG){
    // ================= lm-head consumer WGs (bids 120..239) =================
    const int lw = bid - NWG;       // 0..119
    const int wr = (wid >> 1)*64, wc = (wid & 1)*64;
    for (int q = 0; q < 8; ++q){
      waitf(mfl, 16, q*8 + 8);      // steps q*8 .. q*8+7 published
      // chunk q: 128 logical rows r -> (b = r>>3, t = q*8 + (r&7))
      size_t arow[4];
      #pragma unroll
      for (int i = 0; i < 4; i++){
        int rl = wr + i*16 + l15;
        arow[i] = ((size_t)(rl >> 3)*TT + q*8 + (rl & 7))*DD + kb*8;
      }
      for (int nt = lw; nt < 393; nt += 120){
        int n0 = nt*128;
        size_t brow[4];
        #pragma unroll
        for (int j = 0; j < 4; j++){
          int n = n0 + wc + j*16 + l15;
          if (n > LMN-1) n = LMN-1;
          brow[j] = (size_t)n*LMK + kb*8;
        }
        f32x4 acc[4][4];
        #pragma unroll
        for (int i = 0; i < 4; i++)
          #pragma unroll
          for (int j = 0; j < 4; j++){ f32x4 z = {0.f,0.f,0.f,0.f}; acc[i][j] = z; }
        #pragma unroll 4
        for (int kk = 0; kk < LMK; kk += 32){
          f16x8 af[4], bf[4];
          #pragma unroll
          for (int i = 0; i < 4; i++) af[i] = ld_act16h(hf + arow[i] + kk);
          #pragma unroll
          for (int j = 0; j < 4; j++) bf[j] = *(const f16x8*)(lmw16 + brow[j] + kk);
          #pragma unroll
          for (int i = 0; i < 4; i++)
            #pragma unroll
            for (int j = 0; j < 4; j++)
              acc[i][j] = __builtin_amdgcn_mfma_f32_16x16x32_f16(af[i], bf[j], acc[i][j], 0, 0, 0);
        }
        #pragma unroll
        for (int i = 0; i < 4; i++){
          #pragma unroll
          for (int j = 0; j < 4; j++){
            #pragma unroll
            for (int r = 0; r < 4; r++){
              int ml = wr + i*16 + kb*4 + r;
              int b = ml >> 3, tt = q*8 + (ml & 7);
              int n = n0 + wc + j*16 + l15;
              if (n < LMN) out[((size_t)b*TT + tt)*LMN + n] = acc[i][j][r];
            }
          }
        }
      }
    }
    return;
  }

  // ================= scan WGs (bids 0..119) =================
  // ---- stage weights into LDS (once) ----
  {
    const f16* src = WAf + (size_t)bid*32*768;
    for (int c = tid; c < 3072; c += 256){
      int row = c/96, kc = c - row*96;
      int off = (row*1536 + kc*16) ^ ((row&7)<<4);
      *(f16x8*)(smem + off) = *(const f16x8*)(src + (size_t)row*768 + kc*8);
    }
    if (bid < 48){
      const f16* s2 = V1tf + (size_t)bid*16*3072;
      for (int c = tid; c < 6144; c += 256){
        int row = c/384, kc = c - row*384;
        int off = (row*6144 + kc*16) ^ ((row&7)<<4);
        *(f16x8*)(smem + 49152 + off) = *(const f16x8*)(s2 + (size_t)row*3072 + kc*8);
      }
    } else if (bid < 72){
      const f16* s2 = Wc1f + (size_t)(bid-48)*32*768;
      for (int c = tid; c < 3072; c += 256){
        int row = c/96, kc = c - row*96;
        int off = (row*1536 + kc*16) ^ ((row&7)<<4);
        *(f16x8*)(smem + 49152 + off) = *(const f16x8*)(s2 + (size_t)row*768 + kc*8);
      }
    } else {
      const f16* s2 = WDf + (size_t)(bid-72)*32*768;
      for (int c = tid; c < 3072; c += 256){
        int row = c/96, kc = c - row*96;
        int off = (row*1536 + kc*16) ^ ((row&7)<<4);
        *(f16x8*)(smem + 49152 + off) = *(const f16x8*)(s2 + (size_t)row*768 + kc*8);
      }
    }
  }
  __syncthreads();

  // ---- t-invariant hoists ----
  const int n_a = bid*32 + (wid>>1)*16 + l15;
  float b1v = 0.f;
  if (bid < 48) b1v = b1[bid*16 + l15];
  float cpb1v = 0.f;
  if (bid >= 48 && bid < 72) cpb1v = cpb1[((bid-48)*2 + (wid>>1))*16 + l15];
  float dbv = 0.f; int n_d = 0;
  if (bid >= 72){
    n_d = ((bid-72)*2 + (wid>>1))*16 + l15;
    dbv = (n_d < 768) ? cpb2[n_d] : bdg[n_d - 768];
  }
  float gb3[3], og3[3], ob3[3];
  if (bid < 16){
    #pragma unroll
    for (int j = 0; j < 3; j++){
      int n = tid + j*256;
      gb3[j] = gateb[n]; og3[j] = outg[n]; ob3[j] = outb[n];
    }
  }

  for (int t = 0; t < TT; ++t){
    const int ep = t + 1;
    // ---- per-step prefetch: stage-A epilogue slice ([t][b][n], coalesced) ----
    f32x4 cv = {0.f,0.f,0.f,0.f};
    if ((wid & 1) == 0 && n_a < 3072){
      const float* p = ctxV0T + (size_t)t*16*3072 + n_a;
      #pragma unroll
      for (int r = 0; r < 4; r++) cv[r] = p[(size_t)(kb*4+r)*3072];
    }

    if (t > 0) waitf(mfl, 16, t);      // hf(t-1) published
    // ==== stage A (all 120 WGs)
    {
      const int u = wid >> 1, kh = wid & 1;
      const int k0 = kh*384 + kb*8;
      f32x4 a = {0.f,0.f,0.f,0.f};
      if (t > 0){
        const f16* ap = hf + ((size_t)l15*TT + (t-1))*DD + k0;
        const int row = u*16 + l15, rowoff = row*1536, sw = (row&7)<<4;
        #pragma unroll
        for (int b = 0; b < 12; b++){
          int wb = (rowoff + (k0 + b*32)*2) ^ sw;
          f16x8 vb = *(const f16x8*)(smem + wb);
          f16x8 va = ld_act16h(ap + b*32);
          a = __builtin_amdgcn_mfma_f32_16x16x32_f16(va, vb, a, 0,0,0);
        }
      }
      red_store(redbuf[wid], lane, a);
    }
    __syncthreads();
    if ((wid & 1) == 0){
      f32x4 s4 = red_sum2(redbuf, lane, wid, wid+1);
      #pragma unroll
      for (int r = 0; r < 4; r++){
        int m = kb*4 + r;
        if (n_a < 3072){
          float hv = geluf(s4[r] + cv[r]);
          st_acth(h1f + (size_t)m*3072 + n_a, hv);
        } else {
          st_actf(tfs + m*DD + (n_a - 3072), s4[r]);
        }
      }
    }
    postf(afl + bid*32, ep);
    // ==== stage B (bids 0..47)
    if (bid < 48){
      waitf(afl, 120, ep);
      const int k0 = wid*768 + kb*8;
      const f16* ap = h1f + (size_t)l15*3072 + k0;
      const int rowoff = l15*6144, sw = (l15&7)<<4;
      f32x4 a = {0.f,0.f,0.f,0.f};
      #pragma unroll
      for (int b = 0; b < 24; b++){
        int wb = (rowoff + (k0 + b*32)*2) ^ sw;
        f16x8 vb = *(const f16x8*)(smem + 49152 + wb);
        f16x8 va = ld_act16h(ap + b*32);
        a = __builtin_amdgcn_mfma_f32_16x16x32_f16(va, vb, a, 0,0,0);
      }
      red_store(redbuf[wid], lane, a);
      __syncthreads();
      if (wid == 0){
        f32x4 s4 = red_sum4(redbuf, lane);
        int n = bid*16 + l15;
        #pragma unroll
        for (int r = 0; r < 4; r++){
          int m = kb*4 + r;
          st_acth(c1f + (size_t)m*DD + n, geluf(s4[r] + b1v));
        }
      }
      postf(bfl + bid*32, ep);
    }
    // ---- combine-slice prefetch (bids 0..15) ----
    float gv[3], cxv[3];
    if (bid < 16){
      #pragma unroll
      for (int j = 0; j < 3; j++){
        size_t o = ((size_t)t*16 + bid)*DD + tid + j*256;
        gv[j] = gctxT[o]; cxv[j] = ctxT[o];
      }
    }
    // ==== stage C (bids 48..71)
    if (bid >= 48 && bid < 72){
      waitf(bfl, 48, ep);
      const int u = wid >> 1, kh = wid & 1;
      const int k0 = kh*384 + kb*8;
      const f16* ap = c1f + (size_t)l15*DD + k0;
      const int row = u*16 + l15, rowoff = row*1536, sw = (row&7)<<4;
      f32x4 a = {0.f,0.f,0.f,0.f};
      float sq = 0.f;
      #pragma unroll
      for (int b = 0; b < 12; b++){
        int wb = (rowoff + (k0 + b*32)*2) ^ sw;
        f16x8 vb = *(const f16x8*)(smem + 49152 + wb);
        f16x8 va = ld_act16h(ap + b*32);
        a = __builtin_amdgcn_mfma_f32_16x16x32_f16(va, vb, a, 0,0,0);
        #pragma unroll
        for (int j = 0; j < 8; j++){ float xv = (float)va[j]; sq = fmaf(xv, xv, sq); }
      }
      sq += __shfl_xor(sq,16); sq += __shfl_xor(sq,32);
      if (lane < 16) normp[wid][lane] = sq;
      red_store(redbuf[wid], lane, a);
      __syncthreads();
      if ((wid & 1) == 0){
        f32x4 s4 = red_sum2(redbuf, lane, wid, wid+1);
        int n = ((bid-48)*2 + (wid>>1))*16 + l15;
        #pragma unroll
        for (int r = 0; r < 4; r++){
          int m = kb*4 + r;
          float nm = normp[wid][m] + normp[wid+1][m];
          float inv = 1.f / fmaxf(sqrtf(nm), 1e-12f);
          st_acth(gcaf + (size_t)m*DD + n, geluf(s4[r]*inv + cpb1v));
        }
      }
      postf(cfl + (bid-48)*32, ep);
    }
    // ==== stage D (bids 72..119)
    if (bid >= 72){
      waitf(cfl, 24, ep);
      const int u = wid >> 1, kh = wid & 1;
      const int k0 = kh*384 + kb*8;
      const f16* ap = gcaf + (size_t)l15*DD + k0;
      const int row = u*16 + l15, rowoff = row*1536, sw = (row&7)<<4;
      f32x4 a = {0.f,0.f,0.f,0.f};
      #pragma unroll
      for (int b = 0; b < 12; b++){
        int wb = (rowoff + (k0 + b*32)*2) ^ sw;
        f16x8 vb = *(const f16x8*)(smem + 49152 + wb);
        f16x8 va = ld_act16h(ap + b*32);
        a = __builtin_amdgcn_mfma_f32_16x16x32_f16(va, vb, a, 0,0,0);
      }
      red_store(redbuf[wid], lane, a);
      __syncthreads();
      if ((wid & 1) == 0){
        f32x4 s4 = red_sum2(redbuf, lane, wid, wid+1);
        #pragma unroll
        for (int r = 0; r < 4; r++){
          int m = kb*4 + r;
          if (n_d < 768) st_actf(cf + m*DD + n_d, s4[r] + dbv);
          else           st_actf(gpre + m*DD + (n_d - 768), s4[r] + dbv);
        }
      }
      postf(dfl + (bid-72)*32, ep);
    }
    // ==== combine (bids 0..15)
    if (bid < 16){
      waitf(dfl, 48, ep);
      int m = bid;
      float vals[3]; float s = 0.f, ss = 0.f;
      #pragma unroll
      for (int j = 0; j < 3; j++){
        int n = tid + j*256;
        float gi = gv[j] + ld_actf(gpre + m*DD + n) + gb3[j];
        float gate = 1.f/(1.f + expf(-gi));
        float v = gate*(ld_actf(cf + m*DD + n) + ld_actf(tfs + m*DD + n)) + (1.f - gate)*cxv[j];
        vals[j] = v; s += v; ss += v*v;
      }
      #pragma unroll
      for (int o = 1; o < 64; o <<= 1){ s += __shfl_xor(s, o); ss += __shfl_xor(ss, o); }
      if (lane == 0){ red[wid] = s; red[4+wid] = ss; }
      __syncthreads();
      s  = red[0]+red[1]+red[2]+red[3];
      ss = red[4]+red[5]+red[6]+red[7];
      float mean = s*(1.f/768.f), var = ss*(1.f/768.f) - mean*mean;
      float rstd = rsqrtf(var + 1e-5f);
      #pragma unroll
      for (int j = 0; j < 3; j++){
        int n = tid + j*256;
        float y = (vals[j]-mean)*rstd*og3[j] + ob3[j];
        y = fminf(5.f, fmaxf(-5.f, y));
        st_acth(hf + ((size_t)m*TT + t)*DD + n, y);
      }
      postf(mfl + bid*32, ep);
    }
  }
}

// ---------------- host ----------------
static inline void gemmH(hipStream_t s, const float* A, int lda, const float* Bw, int ldb, int nrb,
                        int M, int N, int K, int operm, const float* bias, const float* res,
                        float* outF, f16* outH, float scale, int act){
  int my = M/128, nx = (N + 127)/128;
  k_gemm<<<nx*my, 256, 0, s>>>(A, lda, Bw, ldb, nrb, M, N, K, my, operm, bias, res, outF, outH, scale, act);
}

extern "C" void kernel_launch(void* const* d_in, const int* in_sizes, int n_in,
                              void* d_out, int out_size, void* d_ws, size_t ws_size,
                              hipStream_t stream)
{
  (void)in_sizes; (void)n_in; (void)out_size; (void)ws_size;
  const int*   tok = (const int*)d_in[0];
  const float* emb = (const float*)d_in[1];
  const float* pos = (const float*)d_in[2];
  const float* aiw = (const float*)d_in[3];
  const float* aib = (const float*)d_in[4];
  const float* aow = (const float*)d_in[5];
  const float* aob = (const float*)d_in[6];
  const float* fw1 = (const float*)d_in[7];
  const float* fb1 = (const float*)d_in[8];
  const float* fw2 = (const float*)d_in[9];
  const float* fb2 = (const float*)d_in[10];
  const float* n1g = (const float*)d_in[11];
  const float* n1b = (const float*)d_in[12];
  const float* n2g = (const float*)d_in[13];
  const float* n2b = (const float*)d_in[14];
  const float* eng = (const float*)d_in[15];
  const float* enb = (const float*)d_in[16];
  const float* V0  = (const float*)d_in[17];
  const float* b0  = (const float*)d_in[18];
  const float* V1  = (const float*)d_in[19];
  const float* b1  = (const float*)d_in[20];
  const float* cw1 = (const float*)d_in[21];
  const float* cb1 = (const float*)d_in[22];
  const float* cw2 = (const float*)d_in[23];
  const float* cb2 = (const float*)d_in[24];
  const float* gw  = (const float*)d_in[25];
  const float* gb  = (const float*)d_in[26];
  const float* tw  = (const float*)d_in[27];
  const float* Rm  = (const float*)d_in[28];
  const float* og  = (const float*)d_in[29];
  const float* ob  = (const float*)d_in[30];
  const float* lmw = (const float*)d_in[31];
  float* out = (float*)d_out;

  char* base = (char*)d_ws; size_t off = 0;
  auto alloc = [&](size_t bytes)->void*{
    off = (off + 255) & ~(size_t)255; void* p = base + off; off += bytes; return p; };

  float* x     = (float*)alloc((size_t)MR*DD*4);
  float* xn    = (float*)alloc((size_t)MR*DD*4);
  float* qkv   = (float*)alloc((size_t)MR*2304*4);
  float* o_    = (float*)alloc((size_t)MR*DD*4);
  float* mid   = (float*)alloc((size_t)MR*2048*4);
  float* ctx   = (float*)alloc((size_t)MR*DD*4);
  float* ctxT  = (float*)alloc((size_t)MR*DD*4);
  float* V0t   = (float*)alloc((size_t)3072*768*4);
  float* cw2t  = (float*)alloc((size_t)768*768*4);
  float* ctxV0T= (float*)alloc((size_t)MR*3072*4);
  float* gctxT = (float*)alloc((size_t)MR*DD*4);
  float* bdg   = (float*)alloc(768*4);
  f16*   WAf   = (f16*)alloc((size_t)3840*768*2);
  f16*   V1tf  = (f16*)alloc((size_t)768*3072*2);
  f16*   Wc1f  = (f16*)alloc((size_t)768*768*2);
  f16*   WDf   = (f16*)alloc((size_t)1536*768*2);
  f16*   lmw16 = (f16*)alloc((size_t)LMN*768*2);
  f16*   hf    = (f16*)alloc((size_t)MR*DD*2);
  f16*   h1f   = (f16*)alloc((size_t)16*3072*2);
  f16*   c1f   = (f16*)alloc((size_t)16*768*2);
  f16*   gcaf  = (f16*)alloc((size_t)16*768*2);
  float* cf    = (float*)alloc((size_t)16*768*4);
  float* gpre  = (float*)alloc((size_t)16*768*4);
  float* tfs   = (float*)alloc((size_t)16*768*4);
  int*   flags = (int*)alloc((size_t)256*32*4);

  // ----- encoder -----
  k_embed<<<MR, 256, 0, stream>>>(tok, emb, pos, x);
  for (int l = 0; l < 2; l++){
    k_ln<false><<<MR, 256, 0, stream>>>(x, n1g + l*768, n1b + l*768, xn, nullptr);
    gemmH(stream, xn, 768, aiw + (size_t)l*2304*768, 768, 2304, MR, 2304, 768, 0,
         aib + l*2304, nullptr, qkv, nullptr, 1.f, 0);
    k_attn<<<128, 256, 0, stream>>>(qkv, o_);
    gemmH(stream, o_, 768, aow + (size_t)l*768*768, 768, 768, MR, 768, 768, 0,
         aob + l*768, x, x, nullptr, 1.f, 0);
    k_ln<false><<<MR, 256, 0, stream>>>(x, n2g + l*768, n2b + l*768, xn, nullptr);
    gemmH(stream, xn, 768, fw1 + (size_t)l*2048*768, 768, 2048, MR, 2048, 768, 0,
         fb1 + l*2048, nullptr, mid, nullptr, 1.f, 1);
    gemmH(stream, mid, 2048, fw2 + (size_t)l*768*2048, 2048, 768, MR, 768, 2048, 0,
         fb2 + l*768, x, x, nullptr, 1.f, 0);
  }
  k_ln<true><<<MR, 256, 0, stream>>>(x, eng, enb, ctx, ctxT);

  // ----- precompute -----
  k_transpose_f<<<dim3(3072/32, 768/32), 256, 0, stream>>>(V0, V0t, 768, 3072);
  k_transpose_f<<<dim3(768/32, 768/32), 256, 0, stream>>>(cw2, cw2t, 768, 768);
  k_transpose_h<<<dim3(768/32, 3072/32), 256, 0, stream>>>(V1, V1tf, 3072, 768);
  k_cast_h<<<(768*768 + 255)/256, 256, 0, stream>>>(cw1, Wc1f, 768*768);
  k_cast_h<<<(768*768 + 255)/256, 256, 0, stream>>>(cw2, WDf, 768*768);
  k_cast_h8<<<((LMN*768/8) + 255)/256, 256, 0, stream>>>(lmw, lmw16, LMN*768/8);
  k_bdg<<<3, 256, 0, stream>>>(gw, cb2, bdg);
  gemmH(stream, V0t, 768, Rm, 768, 768, 3072, 768, 768, 0, nullptr, nullptr,
       nullptr, WAf, ALPHAF, 0);
  gemmH(stream, tw, 768, Rm, 768, 768, 768, 768, 768, 0, nullptr, nullptr,
       nullptr, WAf + (size_t)3072*768, ALPHAF, 0);
  // ctxV0T[t][b][n] = (ctx@V0 + b0)
  gemmH(stream, ctx, 768, V0t, 768, 3072, MR, 3072, 768, 1, b0, nullptr,
       ctxV0T, nullptr, 1.f, 0);
  // gctxT[t][b][n] = ctx @ gate_w[:, :768]^T
  gemmH(stream, ctx, 768, gw, 1536, 768, MR, 768, 768, 1, nullptr, nullptr,
       gctxT, nullptr, 1.f, 0);
  gemmH(stream, gw + 768, 1536, cw2t, 768, 768, 768, 768, 768, 0, nullptr, nullptr,
       nullptr, WDf + (size_t)768*768, 1.f, 0);

  // ----- recurrence + fused lm-head -----
  k_init<<<1, 256, 0, stream>>>(flags);
  k_scan<<<240, 256, 0, stream>>>(WAf, V1tf, Wc1f, WDf,
      ctxV0T, gctxT, ctxT, b1, cb1, cb2, bdg, gb, og, ob,
      hf, h1f, c1f, gcaf, cf, gpre, tfs, flags, lmw16, out);
}

// Round 12
// 3446.164 us; speedup vs baseline: 1.0918x; 1.0173x over previous
//
#include <hip/hip_runtime.h>
#include <math.h>

typedef _Float16 f16;
typedef f16 f16x8 __attribute__((ext_vector_type(8)));
typedef f16 f16x4 __attribute__((ext_vector_type(4)));
typedef float f32x4 __attribute__((ext_vector_type(4)));
typedef unsigned int u32;
typedef unsigned long long u64;

#define TT 64
#define DD 768
#define MR 1024
#define ALPHAF 0.4f
#define NWG 120      // scan WGs; grid = 240 (120 scan + 120 lm-head consumers)
#define GRID 240
#define LMN 50257
#define LMK 768

__device__ __forceinline__ float geluf(float x){
  return 0.5f*x*(1.0f + erff(x*0.70710678118654752f));
}

// ---- coherent (agent-scope, LLC) accessors ----
__device__ __forceinline__ u64 ld_a64(const void* p){
  return __hip_atomic_load((const u64*)p, __ATOMIC_RELAXED, __HIP_MEMORY_SCOPE_AGENT);
}
__device__ __forceinline__ f16x8 ld_act16h(const f16* p){
  union { u64 u[2]; f16x8 v; } c;
  c.u[0] = ld_a64(p); c.u[1] = ld_a64(p + 4); return c.v;
}
__device__ __forceinline__ float ld_actf(const float* p){
  union { u32 u; float f; } c;
  c.u = __hip_atomic_load((const u32*)p, __ATOMIC_RELAXED, __HIP_MEMORY_SCOPE_AGENT);
  return c.f;
}
__device__ __forceinline__ void st_actf(float* p, float v){
  union { u32 u; float f; } c; c.f = v;
  __hip_atomic_store((u32*)p, c.u, __ATOMIC_RELAXED, __HIP_MEMORY_SCOPE_AGENT);
}
__device__ __forceinline__ void st_acth(f16* p, float v){
  union { unsigned short u; f16 h; } c; c.h = (f16)v;
  __hip_atomic_store((unsigned short*)p, c.u, __ATOMIC_RELAXED, __HIP_MEMORY_SCOPE_AGENT);
}

// ---- encoder phase barrier: release wbl2 -> post -> poll -> joint sync -> acquire inv ----
__device__ __forceinline__ void egbar(int* ef, int ep){
  __syncthreads();                     // drains vmcnt per wave (stores in L2)
  if (threadIdx.x == 0){
    __threadfence();                   // writeback XCD L2 -> LLC
    __hip_atomic_store(ef + blockIdx.x*32, ep, __ATOMIC_RELAXED, __HIP_MEMORY_SCOPE_AGENT);
  }
  {
    int id = threadIdx.x; bool active = id < GRID;
    const int* fp = ef + id*32;
    while (true){
      int v = active ? __hip_atomic_load(fp, __ATOMIC_RELAXED, __HIP_MEMORY_SCOPE_AGENT) : ep;
      if (__ballot(v >= ep) == ~0ull) break;
      __builtin_amdgcn_s_sleep(1);
    }
  }
  __syncthreads();                     // ALL flags observed by the WG
  if (threadIdx.x == 0) __threadfence();  // invalidate stale L1/L2
  __syncthreads();
}

// ---- scan flag primitives (agent-scope data path; unchanged from r11) ----
__device__ __forceinline__ void postf(int* f, int ep){
  asm volatile("s_waitcnt vmcnt(0)" ::: "memory");
  __syncthreads();
  if (threadIdx.x == 0)
    __hip_atomic_store(f, ep, __ATOMIC_RELAXED, __HIP_MEMORY_SCOPE_AGENT);
}
__device__ __forceinline__ void waitf(const int* f, int n, int ep){
  if (threadIdx.x < 64){
    int lane = threadIdx.x;
    while (true){
      bool ok = true;
      for (int i = lane; i < n; i += 64){
        if (__hip_atomic_load(f + i*32, __ATOMIC_RELAXED, __HIP_MEMORY_SCOPE_AGENT) < ep){
          ok = false; break;
        }
      }
      if (__ballot(ok) == ~0ull) break;
      __builtin_amdgcn_s_sleep(1);
    }
  }
  __syncthreads();
}

__device__ __forceinline__ void red_store(float* rb, int lane, f32x4 a){
  rb[lane] = a[0]; rb[64+lane] = a[1]; rb[128+lane] = a[2]; rb[192+lane] = a[3];
}
__device__ __forceinline__ f32x4 red_sum4(float rb[4][256], int lane){
  f32x4 s;
  #pragma unroll
  for (int r = 0; r < 4; r++)
    s[r] = rb[0][r*64+lane] + rb[1][r*64+lane] + rb[2][r*64+lane] + rb[3][r*64+lane];
  return s;
}
__device__ __forceinline__ f32x4 red_sum2(float rb[4][256], int lane, int w0, int w1){
  f32x4 s;
  #pragma unroll
  for (int r = 0; r < 4; r++)
    s[r] = rb[w0][r*64+lane] + rb[w1][r*64+lane];
  return s;
}

// ---- device phase helpers ----
__device__ void dev_ln(const float* xr, const float* g, const float* b,
                       float* outr, float* outTr, float* red, bool l2n){
  int tid = threadIdx.x, lane = tid & 63, wid = tid >> 6;
  float v[3]; float s = 0.f, ss = 0.f;
  #pragma unroll
  for (int j = 0; j < 3; j++){ float t0 = xr[tid + j*256]; v[j] = t0; s += t0; ss += t0*t0; }
  #pragma unroll
  for (int o = 1; o < 64; o <<= 1){ s += __shfl_xor(s, o); ss += __shfl_xor(ss, o); }
  if (lane == 0){ red[wid] = s; red[4+wid] = ss; }
  __syncthreads();
  s  = red[0]+red[1]+red[2]+red[3];
  ss = red[4]+red[5]+red[6]+red[7];
  float mean = s*(1.f/768.f);
  float var  = ss*(1.f/768.f) - mean*mean;
  float rstd = rsqrtf(var + 1e-5f);
  float y[3];
  #pragma unroll
  for (int j = 0; j < 3; j++){ int n = tid + j*256; y[j] = (v[j]-mean)*rstd*g[n] + b[n]; }
  if (l2n){
    float n2 = y[0]*y[0] + y[1]*y[1] + y[2]*y[2];
    #pragma unroll
    for (int o = 1; o < 64; o <<= 1) n2 += __shfl_xor(n2, o);
    __syncthreads();
    if (lane == 0) red[wid] = n2;
    __syncthreads();
    n2 = red[0]+red[1]+red[2]+red[3];
    float inv = 1.f / fmaxf(sqrtf(n2), 1e-12f);
    y[0] *= inv; y[1] *= inv; y[2] *= inv;
  }
  #pragma unroll
  for (int j = 0; j < 3; j++) outr[tid + j*256] = y[j];
  if (outTr){
    #pragma unroll
    for (int j = 0; j < 3; j++) outTr[tid + j*256] = y[j];
  }
  __syncthreads();   // protect red[] reuse across rows
}

// 128x128 GEMM tile: C = act(scale*A@B^T + bias) + res; operm 0:[m][n], 1:[t][b][n]
__device__ void dev_gemm_tile(char* lds, const float* A, int lda,
    const float* Bw, int ldb, int nrb, int N, int K, int m0, int n0,
    const float* bias, const float* res, float* outF, f16* outH,
    float scale, int act, int operm)
{
  f16 (*As)[40] = (f16(*)[40])lds;
  f16 (*Bs)[40] = (f16(*)[40])(lds + 10240);
  int tid = threadIdx.x;
  int lane = tid & 63, wid = tid >> 6;
  int wr = (wid >> 1)*64, wc = (wid & 1)*64;
  int l15 = lane & 15, kb = lane >> 4;
  f32x4 acc[4][4];
  #pragma unroll
  for (int i = 0; i < 4; i++)
    #pragma unroll
    for (int j = 0; j < 4; j++){ f32x4 z = {0.f,0.f,0.f,0.f}; acc[i][j] = z; }
  int rA = tid >> 3;
  int k4 = (tid & 7)*4;
  for (int kk = 0; kk < K; kk += 32){
    #pragma unroll
    for (int it = 0; it < 4; ++it){
      int r = it*32 + rA;
      float4 va = *(const float4*)(A + (size_t)(m0+r)*lda + kk + k4);
      *(f16x4*)(&As[r][k4]) = (f16x4){(f16)va.x,(f16)va.y,(f16)va.z,(f16)va.w};
      int rB = n0 + r;
      float4 vb;
      if (rB < nrb) vb = *(const float4*)(Bw + (size_t)rB*ldb + kk + k4);
      else { vb.x = 0.f; vb.y = 0.f; vb.z = 0.f; vb.w = 0.f; }
      *(f16x4*)(&Bs[r][k4]) = (f16x4){(f16)vb.x,(f16)vb.y,(f16)vb.z,(f16)vb.w};
    }
    __syncthreads();
    f16x8 af[4], bfv[4];
    #pragma unroll
    for (int i = 0; i < 4; i++) af[i]  = *(const f16x8*)(&As[wr + i*16 + l15][kb*8]);
    #pragma unroll
    for (int j = 0; j < 4; j++) bfv[j] = *(const f16x8*)(&Bs[wc + j*16 + l15][kb*8]);
    #pragma unroll
    for (int i = 0; i < 4; i++)
      #pragma unroll
      for (int j = 0; j < 4; j++)
        acc[i][j] = __builtin_amdgcn_mfma_f32_16x16x32_f16(af[i], bfv[j], acc[i][j], 0, 0, 0);
    __syncthreads();
  }
  #pragma unroll
  for (int i = 0; i < 4; i++){
    #pragma unroll
    for (int j = 0; j < 4; j++){
      #pragma unroll
      for (int r = 0; r < 4; r++){
        int m = m0 + wr + i*16 + kb*4 + r;
        int n = n0 + wc + j*16 + l15;
        if (n < N){
          float v = acc[i][j][r]*scale;
          if (bias) v += bias[n];
          if (act == 1) v = geluf(v);
          if (res) v += res[(size_t)m*N + n];
          size_t off;
          if (operm == 0) off = (size_t)m*N + n;
          else            off = ((size_t)(m & 63)*16 + (m >> 6))*N + n;
          if (outF) outF[off] = v;
          if (outH) outH[off] = (f16)v;
        }
      }
    }
  }
}

__device__ void dev_attn(char* lds, const float* qkv, float* o, int bh){
  float (*kv)[96] = (float(*)[96])lds;
  float (*sm)[68] = (float(*)[68])(lds + 24576);
  int b = bh >> 3, h = bh & 7;
  int tid = threadIdx.x;
  const float* base = qkv + (size_t)b*64*2304 + h*96;
  for (int idx = tid; idx < 64*96; idx += 256){ int i = idx/96, d = idx - i*96;
    kv[i][d] = base[(size_t)i*2304 + 768 + d]; }
  __syncthreads();
  {
    int i = tid >> 2;
    const float* q = base + (size_t)i*2304;
    int j0 = (tid & 3)*16;
    for (int jj = 0; jj < 16; jj++){
      int j = j0 + jj;
      float sv = -1e30f;
      if (j <= i){ float acc = 0.f;
        for (int d = 0; d < 96; d++) acc += q[d]*kv[j][d];
        sv = acc*0.10206207261596576f; }
      sm[i][j] = sv;
    }
  }
  __syncthreads();
  for (int idx = tid; idx < 64*96; idx += 256){ int i = idx/96, d = idx - i*96;
    kv[i][d] = base[(size_t)i*2304 + 1536 + d]; }
  if (tid < 64){
    int i = tid;
    float mx = -1e30f;
    for (int j = 0; j <= i; j++) mx = fmaxf(mx, sm[i][j]);
    float sum = 0.f;
    for (int j = 0; j <= i; j++){ float e = expf(sm[i][j]-mx); sm[i][j] = e; sum += e; }
    float inv = 1.f/sum;
    for (int j = 0; j <= i; j++) sm[i][j] *= inv;
  }
  __syncthreads();
  for (int idx = tid; idx < 64*96; idx += 256){
    int i = idx/96, d = idx - i*96;
    float acc = 0.f;
    for (int j = 0; j <= i; j++) acc += sm[i][j]*kv[j][d];
    o[(size_t)(b*64+i)*768 + h*96 + d] = acc;
  }
  __syncthreads();
}

__device__ void dev_tr_f(char* lds, const float* in, float* out, int R, int C, int bx, int by){
  float (*tile)[33] = (float(*)[33])lds;
  int r0 = by*32, c0 = bx*32;
  int tx = threadIdx.x & 31, ty = threadIdx.x >> 5;
  #pragma unroll
  for (int i = 0; i < 32; i += 8) tile[ty+i][tx] = in[(size_t)(r0+ty+i)*C + (c0+tx)];
  __syncthreads();
  #pragma unroll
  for (int i = 0; i < 32; i += 8) out[(size_t)(c0+ty+i)*R + (r0+tx)] = tile[tx][ty+i];
  __syncthreads();
}
__device__ void dev_tr_h(char* lds, const float* in, f16* out, int R, int C, int bx, int by){
  float (*tile)[33] = (float(*)[33])lds;
  int r0 = by*32, c0 = bx*32;
  int tx = threadIdx.x & 31, ty = threadIdx.x >> 5;
  #pragma unroll
  for (int i = 0; i < 32; i += 8) tile[ty+i][tx] = in[(size_t)(r0+ty+i)*C + (c0+tx)];
  __syncthreads();
  #pragma unroll
  for (int i = 0; i < 32; i += 8) out[(size_t)(c0+ty+i)*R + (r0+tx)] = (f16)tile[tx][ty+i];
  __syncthreads();
}

__global__ void k_init(int* flags){
  for (int i = threadIdx.x; i < 512*32; i += 256) flags[i] = 0;
}

// =================== MEGA KERNEL ===================
__global__ __launch_bounds__(256, 1) void k_all(
  const int* tok, const float* emb, const float* pos,
  const float* aiw, const float* aib, const float* aow, const float* aob,
  const float* fw1, const float* fb1, const float* fw2, const float* fb2,
  const float* n1g, const float* n1b, const float* n2g, const float* n2b,
  const float* eng, const float* enb,
  const float* V0, const float* b0, const float* V1, const float* b1,
  const float* cw1, const float* cb1, const float* cw2, const float* cb2,
  const float* gw, const float* gb_, const float* tw, const float* Rm,
  const float* og, const float* ob, const float* lmw,
  float* x, float* xn, float* qkv, float* o_, float* mid,
  float* ctx, float* ctxT, float* V0t, float* cw2t,
  float* ctxV0T, float* gctxT, float* bdg,
  f16* WAf, f16* V1tf, f16* Wc1f, f16* WDf, f16* lmw16,
  f16* hf, f16* h1f, f16* c1f, f16* gcaf,
  float* cf, float* gpre, float* tfs, int* flags, float* out)
{
  __shared__ __align__(16) char smem[147456];
  __shared__ float redbuf[4][256];
  __shared__ float normp[4][16];
  __shared__ float red[8];
  const int tid = threadIdx.x, lane = tid & 63, wid = tid >> 6;
  const int bid = blockIdx.x;
  const int l15 = lane & 15, kb = lane >> 4;
  int* afl = flags;
  int* bfl = flags + 120*32;
  int* cfl = flags + 168*32;
  int* dfl = flags + 192*32;
  int* mfl = flags + 240*32;
  int* encf = flags + 256*32;
  int eep = 0;

  // ===== P0: embed =====
  for (int m = bid; m < MR; m += GRID){
    int t = m & 63; int id = tok[m];
    const float* e = emb + (size_t)id*DD;
    const float* p = pos + (size_t)t*DD;
    float* xr = x + (size_t)m*DD;
    for (int j = tid; j < DD; j += 256) xr[j] = e[j] + p[j];
  }
  egbar(encf, ++eep);

  // ===== encoder layers =====
  for (int l = 0; l < 2; l++){
    for (int m = bid; m < MR; m += GRID)
      dev_ln(x + (size_t)m*DD, n1g + l*DD, n1b + l*DD, xn + (size_t)m*DD, nullptr, red, false);
    egbar(encf, ++eep);
    for (int tl = bid; tl < 144; tl += GRID)
      dev_gemm_tile(smem, xn, 768, aiw + (size_t)l*2304*768, 768, 2304, 2304, 768,
                    (tl % 8)*128, (tl / 8)*128, aib + l*2304, nullptr, qkv, nullptr, 1.f, 0, 0);
    egbar(encf, ++eep);
    for (int u = bid; u < 128; u += GRID) dev_attn(smem, qkv, o_, u);
    egbar(encf, ++eep);
    for (int tl = bid; tl < 48; tl += GRID)
      dev_gemm_tile(smem, o_, 768, aow + (size_t)l*768*768, 768, 768, 768, 768,
                    (tl % 8)*128, (tl / 8)*128, aob + l*768, x, x, nullptr, 1.f, 0, 0);
    egbar(encf, ++eep);
    for (int m = bid; m < MR; m += GRID)
      dev_ln(x + (size_t)m*DD, n2g + l*DD, n2b + l*DD, xn + (size_t)m*DD, nullptr, red, false);
    egbar(encf, ++eep);
    for (int tl = bid; tl < 128; tl += GRID)
      dev_gemm_tile(smem, xn, 768, fw1 + (size_t)l*2048*768, 768, 2048, 2048, 768,
                    (tl % 8)*128, (tl / 8)*128, fb1 + l*2048, nullptr, mid, nullptr, 1.f, 1, 0);
    egbar(encf, ++eep);
    for (int tl = bid; tl < 48; tl += GRID)
      dev_gemm_tile(smem, mid, 2048, fw2 + (size_t)l*768*2048, 2048, 768, 768, 2048,
                    (tl % 8)*128, (tl / 8)*128, fb2 + l*768, x, x, nullptr, 1.f, 0, 0);
    egbar(encf, ++eep);
  }
  // ===== final LN + l2norm (+ctxT) =====
  for (int m = bid; m < MR; m += GRID)
    dev_ln(x + (size_t)m*DD, eng, enb, ctx + (size_t)m*DD,
           ctxT + ((size_t)(m & 63)*16 + (m >> 6))*DD, red, true);
  egbar(encf, ++eep);

  // ===== P17: transposes + casts + bdg =====
  for (int task = bid; task < 5184; task += GRID){
    if (task < 2304)      dev_tr_f(smem, V0, V0t, 768, 3072, task % 96, task / 96);
    else if (task < 2880){ int t2 = task - 2304; dev_tr_f(smem, cw2, cw2t, 768, 768, t2 % 24, t2 / 24); }
    else                 { int t2 = task - 2880; dev_tr_h(smem, V1, V1tf, 3072, 768, t2 % 24, t2 / 24); }
  }
  {
    const int g0 = bid*256 + tid, stride = GRID*256;
    for (int i = g0; i < 73728; i += stride){
      float4 a = ((const float4*)cw1)[i*2]; float4 b2 = ((const float4*)cw1)[i*2+1];
      ((f16x8*)Wc1f)[i] = (f16x8){(f16)a.x,(f16)a.y,(f16)a.z,(f16)a.w,(f16)b2.x,(f16)b2.y,(f16)b2.z,(f16)b2.w};
    }
    for (int i = g0; i < 73728; i += stride){
      float4 a = ((const float4*)cw2)[i*2]; float4 b2 = ((const float4*)cw2)[i*2+1];
      ((f16x8*)WDf)[i] = (f16x8){(f16)a.x,(f16)a.y,(f16)a.z,(f16)a.w,(f16)b2.x,(f16)b2.y,(f16)b2.z,(f16)b2.w};
    }
    for (int i = g0; i < (LMN*768/8); i += stride){
      float4 a = ((const float4*)lmw)[i*2]; float4 b2 = ((const float4*)lmw)[i*2+1];
      ((f16x8*)lmw16)[i] = (f16x8){(f16)a.x,(f16)a.y,(f16)a.z,(f16)a.w,(f16)b2.x,(f16)b2.y,(f16)b2.z,(f16)b2.w};
    }
    for (int g = g0; g < 768; g += stride){
      const float* row = gw + (size_t)g*1536 + 768;
      float s = 0.f;
      for (int j = 0; j < 768; j++) s += cb2[j]*row[j];
      bdg[g] = s;
    }
  }
  egbar(encf, ++eep);

  // ===== P18: precompute GEMMs (456 tiles) =====
  for (int task = bid; task < 456; task += GRID){
    if (task < 144)
      dev_gemm_tile(smem, V0t, 768, Rm, 768, 768, 768, 768,
                    (task % 24)*128, (task / 24)*128, nullptr, nullptr, nullptr, WAf, ALPHAF, 0, 0);
    else if (task < 180){ int t2 = task - 144;
      dev_gemm_tile(smem, tw, 768, Rm, 768, 768, 768, 768,
                    (t2 % 6)*128, (t2 / 6)*128, nullptr, nullptr, nullptr, WAf + (size_t)3072*768, ALPHAF, 0, 0); }
    else if (task < 372){ int t2 = task - 180;
      dev_gemm_tile(smem, ctx, 768, V0t, 768, 3072, 3072, 768,
                    (t2 % 8)*128, (t2 / 8)*128, b0, nullptr, ctxV0T, nullptr, 1.f, 0, 1); }
    else if (task < 420){ int t2 = task - 372;
      dev_gemm_tile(smem, ctx, 768, gw, 1536, 768, 768, 768,
                    (t2 % 8)*128, (t2 / 8)*128, nullptr, nullptr, gctxT, nullptr, 1.f, 0, 1); }
    else { int t2 = task - 420;
      dev_gemm_tile(smem, gw + 768, 1536, cw2t, 768, 768, 768, 768,
                    (t2 % 6)*128, (t2 / 6)*128, nullptr, nullptr, nullptr, WDf + (size_t)768*768, 1.f, 0, 0); }
  }
  egbar(encf, ++eep);

  // ===================== lm-head consumers =====================
  if (bid >= NWG){
    const int lw = bid - NWG;
    const int wr = (wid >> 1)*64, wc = (wid & 1)*64;
    for (int q = 0; q < 8; ++q){
      waitf(mfl, 16, q*8 + 8);
      size_t arow[4];
      #pragma unroll
      for (int i = 0; i < 4; i++){
        int rl = wr + i*16 + l15;
        arow[i] = ((size_t)(rl >> 3)*TT + q*8 + (rl & 7))*DD + kb*8;
      }
      for (int nt = lw; nt < 393; nt += 120){
        int n0 = nt*128;
        size_t brow[4];
        #pragma unroll
        for (int j = 0; j < 4; j++){
          int n = n0 + wc + j*16 + l15;
          if (n > LMN-1) n = LMN-1;
          brow[j] = (size_t)n*LMK + kb*8;
        }
        f32x4 acc[4][4];
        #pragma unroll
        for (int i = 0; i < 4; i++)
          #pragma unroll
          for (int j = 0; j < 4; j++){ f32x4 z = {0.f,0.f,0.f,0.f}; acc[i][j] = z; }
        #pragma unroll 4
        for (int kk = 0; kk < LMK; kk += 32){
          f16x8 af[4], bf[4];
          #pragma unroll
          for (int i = 0; i < 4; i++) af[i] = ld_act16h(hf + arow[i] + kk);
          #pragma unroll
          for (int j = 0; j < 4; j++) bf[j] = *(const f16x8*)(lmw16 + brow[j] + kk);
          #pragma unroll
          for (int i = 0; i < 4; i++)
            #pragma unroll
            for (int j = 0; j < 4; j++)
              acc[i][j] = __builtin_amdgcn_mfma_f32_16x16x32_f16(af[i], bf[j], acc[i][j], 0, 0, 0);
        }
        #pragma unroll
        for (int i = 0; i < 4; i++){
          #pragma unroll
          for (int j = 0; j < 4; j++){
            #pragma unroll
            for (int r = 0; r < 4; r++){
              int ml = wr + i*16 + kb*4 + r;
              int b = ml >> 3, tt = q*8 + (ml & 7);
              int n = n0 + wc + j*16 + l15;
              if (n < LMN) out[((size_t)b*TT + tt)*LMN + n] = acc[i][j][r];
            }
          }
        }
      }
    }
    return;
  }

  // ===================== scan WGs (bids 0..119) =====================
  // ---- stage weights into LDS ----
  {
    const f16* src = WAf + (size_t)bid*32*768;
    for (int c = tid; c < 3072; c += 256){
      int row = c/96, kc = c - row*96;
      int off = (row*1536 + kc*16) ^ ((row&7)<<4);
      *(f16x8*)(smem + off) = *(const f16x8*)(src + (size_t)row*768 + kc*8);
    }
    if (bid < 48){
      const f16* s2 = V1tf + (size_t)bid*16*3072;
      for (int c = tid; c < 6144; c += 256){
        int row = c/384, kc = c - row*384;
        int off = (row*6144 + kc*16) ^ ((row&7)<<4);
        *(f16x8*)(smem + 49152 + off) = *(const f16x8*)(s2 + (size_t)row*3072 + kc*8);
      }
    } else if (bid < 72){
      const f16* s2 = Wc1f + (size_t)(bid-48)*32*768;
      for (int c = tid; c < 3072; c += 256){
        int row = c/96, kc = c - row*96;
        int off = (row*1536 + kc*16) ^ ((row&7)<<4);
        *(f16x8*)(smem + 49152 + off) = *(const f16x8*)(s2 + (size_t)row*768 + kc*8);
      }
    } else {
      const f16* s2 = WDf + (size_t)(bid-72)*32*768;
      for (int c = tid; c < 3072; c += 256){
        int row = c/96, kc = c - row*96;
        int off = (row*1536 + kc*16) ^ ((row&7)<<4);
        *(f16x8*)(smem + 49152 + off) = *(const f16x8*)(s2 + (size_t)row*768 + kc*8);
      }
    }
  }
  __syncthreads();

  // ---- t-invariant hoists ----
  const int n_a = bid*32 + (wid>>1)*16 + l15;
  float b1v = 0.f;
  if (bid < 48) b1v = b1[bid*16 + l15];
  float cpb1v = 0.f;
  if (bid >= 48 && bid < 72) cpb1v = cb1[((bid-48)*2 + (wid>>1))*16 + l15];
  float dbv = 0.f; int n_d = 0;
  if (bid >= 72){
    n_d = ((bid-72)*2 + (wid>>1))*16 + l15;
    dbv = (n_d < 768) ? cb2[n_d] : bdg[n_d - 768];
  }
  float gb3[3], og3[3], ob3[3];
  if (bid < 16){
    #pragma unroll
    for (int j = 0; j < 3; j++){
      int n = tid + j*256;
      gb3[j] = gb_[n]; og3[j] = og[n]; ob3[j] = ob[n];
    }
  }

  for (int t = 0; t < TT; ++t){
    const int ep = t + 1;
    f32x4 cv = {0.f,0.f,0.f,0.f};
    if ((wid & 1) == 0 && n_a < 3072){
      const float* p = ctxV0T + (size_t)t*16*3072 + n_a;
      #pragma unroll
      for (int r = 0; r < 4; r++) cv[r] = p[(size_t)(kb*4+r)*3072];
    }

    if (t > 0) waitf(mfl, 16, t);
    // ==== stage A
    {
      const int u = wid >> 1, kh = wid & 1;
      const int k0 = kh*384 + kb*8;
      f32x4 a = {0.f,0.f,0.f,0.f};
      if (t > 0){
        const f16* ap = hf + ((size_t)l15*TT + (t-1))*DD + k0;
        const int row = u*16 + l15, rowoff = row*1536, sw = (row&7)<<4;
        #pragma unroll
        for (int b = 0; b < 12; b++){
          int wb = (rowoff + (k0 + b*32)*2) ^ sw;
          f16x8 vb = *(const f16x8*)(smem + wb);
          f16x8 va = ld_act16h(ap + b*32);
          a = __builtin_amdgcn_mfma_f32_16x16x32_f16(va, vb, a, 0,0,0);
        }
      }
      red_store(redbuf[wid], lane, a);
    }
    __syncthreads();
    if ((wid & 1) == 0){
      f32x4 s4 = red_sum2(redbuf, lane, wid, wid+1);
      #pragma unroll
      for (int r = 0; r < 4; r++){
        int m = kb*4 + r;
        if (n_a < 3072){
          float hv = geluf(s4[r] + cv[r]);
          st_acth(h1f + (size_t)m*3072 + n_a, hv);
        } else {
          st_actf(tfs + m*DD + (n_a - 3072), s4[r]);
        }
      }
    }
    postf(afl + bid*32, ep);
    // ==== stage B
    if (bid < 48){
      waitf(afl, 120, ep);
      const int k0 = wid*768 + kb*8;
      const f16* ap = h1f + (size_t)l15*3072 + k0;
      const int rowoff = l15*6144, sw = (l15&7)<<4;
      f32x4 a = {0.f,0.f,0.f,0.f};
      #pragma unroll
      for (int b = 0; b < 24; b++){
        int wb = (rowoff + (k0 + b*32)*2) ^ sw;
        f16x8 vb = *(const f16x8*)(smem + 49152 + wb);
        f16x8 va = ld_act16h(ap + b*32);
        a = __builtin_amdgcn_mfma_f32_16x16x32_f16(va, vb, a, 0,0,0);
      }
      red_store(redbuf[wid], lane, a);
      __syncthreads();
      if (wid == 0){
        f32x4 s4 = red_sum4(redbuf, lane);
        int n = bid*16 + l15;
        #pragma unroll
        for (int r = 0; r < 4; r++){
          int m = kb*4 + r;
          st_acth(c1f + (size_t)m*DD + n, geluf(s4[r] + b1v));
        }
      }
      postf(bfl + bid*32, ep);
    }
    float gv[3], cxv[3];
    if (bid < 16){
      #pragma unroll
      for (int j = 0; j < 3; j++){
        size_t o2 = ((size_t)t*16 + bid)*DD + tid + j*256;
        gv[j] = gctxT[o2]; cxv[j] = ctxT[o2];
      }
    }
    // ==== stage C
    if (bid >= 48 && bid < 72){
      waitf(bfl, 48, ep);
      const int u = wid >> 1, kh = wid & 1;
      const int k0 = kh*384 + kb*8;
      const f16* ap = c1f + (size_t)l15*DD + k0;
      const int row = u*16 + l15, rowoff = row*1536, sw = (row&7)<<4;
      f32x4 a = {0.f,0.f,0.f,0.f};
      float sq = 0.f;
      #pragma unroll
      for (int b = 0; b < 12; b++){
        int wb = (rowoff + (k0 + b*32)*2) ^ sw;
        f16x8 vb = *(const f16x8*)(smem + 49152 + wb);
        f16x8 va = ld_act16h(ap + b*32);
        a = __builtin_amdgcn_mfma_f32_16x16x32_f16(va, vb, a, 0,0,0);
        #pragma unroll
        for (int j = 0; j < 8; j++){ float xv = (float)va[j]; sq = fmaf(xv, xv, sq); }
      }
      sq += __shfl_xor(sq,16); sq += __shfl_xor(sq,32);
      if (lane < 16) normp[wid][lane] = sq;
      red_store(redbuf[wid], lane, a);
      __syncthreads();
      if ((wid & 1) == 0){
        f32x4 s4 = red_sum2(redbuf, lane, wid, wid+1);
        int n = ((bid-48)*2 + (wid>>1))*16 + l15;
        #pragma unroll
        for (int r = 0; r < 4; r++){
          int m = kb*4 + r;
          float nm = normp[wid][m] + normp[wid+1][m];
          float inv = 1.f / fmaxf(sqrtf(nm), 1e-12f);
          st_acth(gcaf + (size_t)m*DD + n, geluf(s4[r]*inv + cpb1v));
        }
      }
      postf(cfl + (bid-48)*32, ep);
    }
    // ==== stage D
    if (bid >= 72){
      waitf(cfl, 24, ep);
      const int u = wid >> 1, kh = wid & 1;
      const int k0 = kh*384 + kb*8;
      const f16* ap = gcaf + (size_t)l15*DD + k0;
      const int row = u*16 + l15, rowoff = row*1536, sw = (row&7)<<4;
      f32x4 a = {0.f,0.f,0.f,0.f};
      #pragma unroll
      for (int b = 0; b < 12; b++){
        int wb = (rowoff + (k0 + b*32)*2) ^ sw;
        f16x8 vb = *(const f16x8*)(smem + 49152 + wb);
        f16x8 va = ld_act16h(ap + b*32);
        a = __builtin_amdgcn_mfma_f32_16x16x32_f16(va, vb, a, 0,0,0);
      }
      red_store(redbuf[wid], lane, a);
      __syncthreads();
      if ((wid & 1) == 0){
        f32x4 s4 = red_sum2(redbuf, lane, wid, wid+1);
        #pragma unroll
        for (int r = 0; r < 4; r++){
          int m = kb*4 + r;
          if (n_d < 768) st_actf(cf + m*DD + n_d, s4[r] + dbv);
          else           st_actf(gpre + m*DD + (n_d - 768), s4[r] + dbv);
        }
      }
      postf(dfl + (bid-72)*32, ep);
    }
    // ==== combine
    if (bid < 16){
      waitf(dfl, 48, ep);
      int m = bid;
      float vals[3]; float s = 0.f, ss = 0.f;
      #pragma unroll
      for (int j = 0; j < 3; j++){
        int n = tid + j*256;
        float gi = gv[j] + ld_actf(gpre + m*DD + n) + gb3[j];
        float gate = 1.f/(1.f + expf(-gi));
        float v = gate*(ld_actf(cf + m*DD + n) + ld_actf(tfs + m*DD + n)) + (1.f - gate)*cxv[j];
        vals[j] = v; s += v; ss += v*v;
      }
      #pragma unroll
      for (int o2 = 1; o2 < 64; o2 <<= 1){ s += __shfl_xor(s, o2); ss += __shfl_xor(ss, o2); }
      if (lane == 0){ red[wid] = s; red[4+wid] = ss; }
      __syncthreads();
      s  = red[0]+red[1]+red[2]+red[3];
      ss = red[4]+red[5]+red[6]+red[7];
      float mean = s*(1.f/768.f), var = ss*(1.f/768.f) - mean*mean;
      float rstd = rsqrtf(var + 1e-5f);
      #pragma unroll
      for (int j = 0; j < 3; j++){
        int n = tid + j*256;
        float y = (vals[j]-mean)*rstd*og3[j] + ob3[j];
        y = fminf(5.f, fmaxf(-5.f, y));
        st_acth(hf + ((size_t)m*TT + t)*DD + n, y);
      }
      postf(mfl + bid*32, ep);
    }
  }
}

// ---------------- host ----------------
extern "C" void kernel_launch(void* const* d_in, const int* in_sizes, int n_in,
                              void* d_out, int out_size, void* d_ws, size_t ws_size,
                              hipStream_t stream)
{
  (void)in_sizes; (void)n_in; (void)out_size; (void)ws_size;
  const int*   tok = (const int*)d_in[0];
  const float* emb = (const float*)d_in[1];
  const float* pos = (const float*)d_in[2];
  const float* aiw = (const float*)d_in[3];
  const float* aib = (const float*)d_in[4];
  const float* aow = (const float*)d_in[5];
  const float* aob = (const float*)d_in[6];
  const float* fw1 = (const float*)d_in[7];
  const float* fb1 = (const float*)d_in[8];
  const float* fw2 = (const float*)d_in[9];
  const float* fb2 = (const float*)d_in[10];
  const float* n1g = (const float*)d_in[11];
  const float* n1b = (const float*)d_in[12];
  const float* n2g = (const float*)d_in[13];
  const float* n2b = (const float*)d_in[14];
  const float* eng = (const float*)d_in[15];
  const float* enb = (const float*)d_in[16];
  const float* V0  = (const float*)d_in[17];
  const float* b0  = (const float*)d_in[18];
  const float* V1  = (const float*)d_in[19];
  const float* b1  = (const float*)d_in[20];
  const float* cw1 = (const float*)d_in[21];
  const float* cb1 = (const float*)d_in[22];
  const float* cw2 = (const float*)d_in[23];
  const float* cb2 = (const float*)d_in[24];
  const float* gw  = (const float*)d_in[25];
  const float* gb  = (const float*)d_in[26];
  const float* tw  = (const float*)d_in[27];
  const float* Rm  = (const float*)d_in[28];
  const float* og  = (const float*)d_in[29];
  const float* ob  = (const float*)d_in[30];
  const float* lmw = (const float*)d_in[31];
  float* out = (float*)d_out;

  char* base = (char*)d_ws; size_t off = 0;
  auto alloc = [&](size_t bytes)->void*{
    off = (off + 255) & ~(size_t)255; void* p = base + off; off += bytes; return p; };

  float* x     = (float*)alloc((size_t)MR*DD*4);
  float* xn    = (float*)alloc((size_t)MR*DD*4);
  float* qkv   = (float*)alloc((size_t)MR*2304*4);
  float* o_    = (float*)alloc((size_t)MR*DD*4);
  float* mid   = (float*)alloc((size_t)MR*2048*4);
  float* ctx   = (float*)alloc((size_t)MR*DD*4);
  float* ctxT  = (float*)alloc((size_t)MR*DD*4);
  float* V0t   = (float*)alloc((size_t)3072*768*4);
  float* cw2t  = (float*)alloc((size_t)768*768*4);
  float* ctxV0T= (float*)alloc((size_t)MR*3072*4);
  float* gctxT = (float*)alloc((size_t)MR*DD*4);
  float* bdg   = (float*)alloc(768*4);
  f16*   WAf   = (f16*)alloc((size_t)3840*768*2);
  f16*   V1tf  = (f16*)alloc((size_t)768*3072*2);
  f16*   Wc1f  = (f16*)alloc((size_t)768*768*2);
  f16*   WDf   = (f16*)alloc((size_t)1536*768*2);
  f16*   lmw16 = (f16*)alloc((size_t)LMN*768*2);
  f16*   hf    = (f16*)alloc((size_t)MR*DD*2);
  f16*   h1f   = (f16*)alloc((size_t)16*3072*2);
  f16*   c1f   = (f16*)alloc((size_t)16*768*2);
  f16*   gcaf  = (f16*)alloc((size_t)16*768*2);
  float* cf    = (float*)alloc((size_t)16*768*4);
  float* gpre  = (float*)alloc((size_t)16*768*4);
  float* tfs   = (float*)alloc((size_t)16*768*4);
  int*   flags = (int*)alloc((size_t)512*32*4);

  k_init<<<1, 256, 0, stream>>>(flags);
  k_all<<<GRID, 256, 0, stream>>>(tok, emb, pos, aiw, aib, aow, aob,
      fw1, fb1, fw2, fb2, n1g, n1b, n2g, n2b, eng, enb,
      V0, b0, V1, b1, cw1, cb1, cw2, cb2, gw, gb, tw, Rm, og, ob, lmw,
      x, xn, qkv, o_, mid, ctx, ctxT, V0t, cw2t, ctxV0T, gctxT, bdg,
      WAf, V1tf, Wc1f, WDf, lmw16, hf, h1f, c1f, gcaf, cf, gpre, tfs, flags, out);
}

// Round 13
// 2698.393 us; speedup vs baseline: 1.3943x; 1.2771x over previous
//
#include <hip/hip_runtime.h>
#include <math.h>

typedef _Float16 f16;
typedef f16 f16x8 __attribute__((ext_vector_type(8)));
typedef f16 f16x4 __attribute__((ext_vector_type(4)));
typedef float f32x4 __attribute__((ext_vector_type(4)));
typedef unsigned int u32;
typedef unsigned long long u64;

#define TT 64
#define DD 768
#define MR 1024
#define ALPHAF 0.4f
#define NWG 120      // scan WGs; grid = 240 (120 scan + 120 lm-head consumers)
#define GRID 240
#define LMN 50257
#define LMK 768

__device__ __forceinline__ float geluf(float x){
  return 0.5f*x*(1.0f + erff(x*0.70710678118654752f));
}

// ---- coherent (agent-scope, LLC) accessors ----
__device__ __forceinline__ u64 ld_a64(const void* p){
  return __hip_atomic_load((const u64*)p, __ATOMIC_RELAXED, __HIP_MEMORY_SCOPE_AGENT);
}
__device__ __forceinline__ f16x8 ld_act16h(const f16* p){
  union { u64 u[2]; f16x8 v; } c;
  c.u[0] = ld_a64(p); c.u[1] = ld_a64(p + 4); return c.v;
}
__device__ __forceinline__ float ld_actf(const float* p){
  union { u32 u; float f; } c;
  c.u = __hip_atomic_load((const u32*)p, __ATOMIC_RELAXED, __HIP_MEMORY_SCOPE_AGENT);
  return c.f;
}
__device__ __forceinline__ void st_actf(float* p, float v){
  union { u32 u; float f; } c; c.f = v;
  __hip_atomic_store((u32*)p, c.u, __ATOMIC_RELAXED, __HIP_MEMORY_SCOPE_AGENT);
}
__device__ __forceinline__ void st_acth(f16* p, float v){
  union { unsigned short u; f16 h; } c; c.h = (f16)v;
  __hip_atomic_store((unsigned short*)p, c.u, __ATOMIC_RELAXED, __HIP_MEMORY_SCOPE_AGENT);
}

// ---- encoder phase barrier ----
__device__ __forceinline__ void egbar(int* ef, int ep){
  __syncthreads();
  if (threadIdx.x == 0){
    __threadfence();
    __hip_atomic_store(ef + blockIdx.x*32, ep, __ATOMIC_RELAXED, __HIP_MEMORY_SCOPE_AGENT);
  }
  {
    int id = threadIdx.x; bool active = id < GRID;
    const int* fp = ef + id*32;
    while (true){
      int v = active ? __hip_atomic_load(fp, __ATOMIC_RELAXED, __HIP_MEMORY_SCOPE_AGENT) : ep;
      if (__ballot(v >= ep) == ~0ull) break;
      __builtin_amdgcn_s_sleep(1);
    }
  }
  __syncthreads();
  if (threadIdx.x == 0) __threadfence();
  __syncthreads();
}

// ---- scan flag primitives ----
__device__ __forceinline__ void postf(int* f, int ep){
  asm volatile("s_waitcnt vmcnt(0)" ::: "memory");
  __syncthreads();
  if (threadIdx.x == 0)
    __hip_atomic_store(f, ep, __ATOMIC_RELAXED, __HIP_MEMORY_SCOPE_AGENT);
}
__device__ __forceinline__ void waitf(const int* f, int n, int ep){
  if (threadIdx.x < 64){
    int lane = threadIdx.x;
    while (true){
      bool ok = true;
      for (int i = lane; i < n; i += 64){
        if (__hip_atomic_load(f + i*32, __ATOMIC_RELAXED, __HIP_MEMORY_SCOPE_AGENT) < ep){
          ok = false; break;
        }
      }
      if (__ballot(ok) == ~0ull) break;
      __builtin_amdgcn_s_sleep(1);
    }
  }
  __syncthreads();
}

__device__ __forceinline__ void red_store(float* rb, int lane, f32x4 a){
  rb[lane] = a[0]; rb[64+lane] = a[1]; rb[128+lane] = a[2]; rb[192+lane] = a[3];
}
__device__ __forceinline__ f32x4 red_sum4(float rb[4][256], int lane){
  f32x4 s;
  #pragma unroll
  for (int r = 0; r < 4; r++)
    s[r] = rb[0][r*64+lane] + rb[1][r*64+lane] + rb[2][r*64+lane] + rb[3][r*64+lane];
  return s;
}
__device__ __forceinline__ f32x4 red_sum2(float rb[4][256], int lane, int w0, int w1){
  f32x4 s;
  #pragma unroll
  for (int r = 0; r < 4; r++)
    s[r] = rb[w0][r*64+lane] + rb[w1][r*64+lane];
  return s;
}

// ---- device phase helpers ----
__device__ void dev_ln(const float* xr, const float* g, const float* b,
                       float* outr, float* outTr, float* red, bool l2n){
  int tid = threadIdx.x, lane = tid & 63, wid = tid >> 6;
  float v[3]; float s = 0.f, ss = 0.f;
  #pragma unroll
  for (int j = 0; j < 3; j++){ float t0 = xr[tid + j*256]; v[j] = t0; s += t0; ss += t0*t0; }
  #pragma unroll
  for (int o = 1; o < 64; o <<= 1){ s += __shfl_xor(s, o); ss += __shfl_xor(ss, o); }
  if (lane == 0){ red[wid] = s; red[4+wid] = ss; }
  __syncthreads();
  s  = red[0]+red[1]+red[2]+red[3];
  ss = red[4]+red[5]+red[6]+red[7];
  float mean = s*(1.f/768.f);
  float var  = ss*(1.f/768.f) - mean*mean;
  float rstd = rsqrtf(var + 1e-5f);
  float y[3];
  #pragma unroll
  for (int j = 0; j < 3; j++){ int n = tid + j*256; y[j] = (v[j]-mean)*rstd*g[n] + b[n]; }
  if (l2n){
    float n2 = y[0]*y[0] + y[1]*y[1] + y[2]*y[2];
    #pragma unroll
    for (int o = 1; o < 64; o <<= 1) n2 += __shfl_xor(n2, o);
    __syncthreads();
    if (lane == 0) red[wid] = n2;
    __syncthreads();
    n2 = red[0]+red[1]+red[2]+red[3];
    float inv = 1.f / fmaxf(sqrtf(n2), 1e-12f);
    y[0] *= inv; y[1] *= inv; y[2] *= inv;
  }
  #pragma unroll
  for (int j = 0; j < 3; j++) outr[tid + j*256] = y[j];
  if (outTr){
    #pragma unroll
    for (int j = 0; j < 3; j++) outTr[tid + j*256] = y[j];
  }
  __syncthreads();
}

// 128x128 GEMM tile, SOFTWARE-PIPELINED: double-buffered LDS (2x20KB) +
// register prefetch of next K-step issued under current step's MFMA.
// One __syncthreads per K-step. operm 0:[m][n], 1:[t][b][n]
__device__ void dev_gemm_tile(char* lds, const float* A, int lda,
    const float* Bw, int ldb, int nrb, int N, int K, int m0, int n0,
    const float* bias, const float* res, float* outF, f16* outH,
    float scale, int act, int operm)
{
  int tid = threadIdx.x;
  int lane = tid & 63, wid = tid >> 6;
  int wr = (wid >> 1)*64, wc = (wid & 1)*64;
  int l15 = lane & 15, kb = lane >> 4;
  f32x4 acc[4][4];
  #pragma unroll
  for (int i = 0; i < 4; i++)
    #pragma unroll
    for (int j = 0; j < 4; j++){ f32x4 z = {0.f,0.f,0.f,0.f}; acc[i][j] = z; }
  int rA = tid >> 3;
  int k4 = (tid & 7)*4;
  float4 va[4], vb[4];
  #pragma unroll
  for (int it = 0; it < 4; ++it){
    int r = it*32 + rA;
    va[it] = *(const float4*)(A + (size_t)(m0+r)*lda + k4);
    int rB = n0 + r;
    if (rB < nrb) vb[it] = *(const float4*)(Bw + (size_t)rB*ldb + k4);
    else { vb[it].x=0.f; vb[it].y=0.f; vb[it].z=0.f; vb[it].w=0.f; }
  }
  for (int kk = 0; kk < K; kk += 32){
    char* cb = lds + (((kk >> 5) & 1) ? 20480 : 0);
    f16 (*As)[40] = (f16(*)[40])cb;
    f16 (*Bs)[40] = (f16(*)[40])(cb + 10240);
    #pragma unroll
    for (int it = 0; it < 4; ++it){
      int r = it*32 + rA;
      *(f16x4*)(&As[r][k4]) = (f16x4){(f16)va[it].x,(f16)va[it].y,(f16)va[it].z,(f16)va[it].w};
      *(f16x4*)(&Bs[r][k4]) = (f16x4){(f16)vb[it].x,(f16)vb[it].y,(f16)vb[it].z,(f16)vb[it].w};
    }
    __syncthreads();
    if (kk + 32 < K){
      #pragma unroll
      for (int it = 0; it < 4; ++it){
        int r = it*32 + rA;
        va[it] = *(const float4*)(A + (size_t)(m0+r)*lda + kk + 32 + k4);
        int rB = n0 + r;
        if (rB < nrb) vb[it] = *(const float4*)(Bw + (size_t)rB*ldb + kk + 32 + k4);
        else { vb[it].x=0.f; vb[it].y=0.f; vb[it].z=0.f; vb[it].w=0.f; }
      }
    }
    f16x8 af[4], bfv[4];
    #pragma unroll
    for (int i = 0; i < 4; i++) af[i]  = *(const f16x8*)(&As[wr + i*16 + l15][kb*8]);
    #pragma unroll
    for (int j = 0; j < 4; j++) bfv[j] = *(const f16x8*)(&Bs[wc + j*16 + l15][kb*8]);
    #pragma unroll
    for (int i = 0; i < 4; i++)
      #pragma unroll
      for (int j = 0; j < 4; j++)
        acc[i][j] = __builtin_amdgcn_mfma_f32_16x16x32_f16(af[i], bfv[j], acc[i][j], 0, 0, 0);
  }
  __syncthreads();
  #pragma unroll
  for (int i = 0; i < 4; i++){
    #pragma unroll
    for (int j = 0; j < 4; j++){
      #pragma unroll
      for (int r = 0; r < 4; r++){
        int m = m0 + wr + i*16 + kb*4 + r;
        int n = n0 + wc + j*16 + l15;
        if (n < N){
          float v = acc[i][j][r]*scale;
          if (bias) v += bias[n];
          if (act == 1) v = geluf(v);
          if (res) v += res[(size_t)m*N + n];
          size_t off;
          if (operm == 0) off = (size_t)m*N + n;
          else            off = ((size_t)(m & 63)*16 + (m >> 6))*N + n;
          if (outF) outF[off] = v;
          if (outH) outH[off] = (f16)v;
        }
      }
    }
  }
}

__device__ void dev_attn(char* lds, const float* qkv, float* o, int bh){
  float (*kv)[96] = (float(*)[96])lds;
  float (*sm)[68] = (float(*)[68])(lds + 24576);
  int b = bh >> 3, h = bh & 7;
  int tid = threadIdx.x;
  const float* base = qkv + (size_t)b*64*2304 + h*96;
  for (int idx = tid; idx < 64*96; idx += 256){ int i = idx/96, d = idx - i*96;
    kv[i][d] = base[(size_t)i*2304 + 768 + d]; }
  __syncthreads();
  {
    int i = tid >> 2;
    const float* q = base + (size_t)i*2304;
    int j0 = (tid & 3)*16;
    for (int jj = 0; jj < 16; jj++){
      int j = j0 + jj;
      float sv = -1e30f;
      if (j <= i){ float acc = 0.f;
        for (int d = 0; d < 96; d++) acc += q[d]*kv[j][d];
        sv = acc*0.10206207261596576f; }
      sm[i][j] = sv;
    }
  }
  __syncthreads();
  for (int idx = tid; idx < 64*96; idx += 256){ int i = idx/96, d = idx - i*96;
    kv[i][d] = base[(size_t)i*2304 + 1536 + d]; }
  if (tid < 64){
    int i = tid;
    float mx = -1e30f;
    for (int j = 0; j <= i; j++) mx = fmaxf(mx, sm[i][j]);
    float sum = 0.f;
    for (int j = 0; j <= i; j++){ float e = expf(sm[i][j]-mx); sm[i][j] = e; sum += e; }
    float inv = 1.f/sum;
    for (int j = 0; j <= i; j++) sm[i][j] *= inv;
  }
  __syncthreads();
  for (int idx = tid; idx < 64*96; idx += 256){
    int i = idx/96, d = idx - i*96;
    float acc = 0.f;
    for (int j = 0; j <= i; j++) acc += sm[i][j]*kv[j][d];
    o[(size_t)(b*64+i)*768 + h*96 + d] = acc;
  }
  __syncthreads();
}

__device__ void dev_tr_f(char* lds, const float* in, float* out, int R, int C, int bx, int by){
  float (*tile)[33] = (float(*)[33])lds;
  int r0 = by*32, c0 = bx*32;
  int tx = threadIdx.x & 31, ty = threadIdx.x >> 5;
  #pragma unroll
  for (int i = 0; i < 32; i += 8) tile[ty+i][tx] = in[(size_t)(r0+ty+i)*C + (c0+tx)];
  __syncthreads();
  #pragma unroll
  for (int i = 0; i < 32; i += 8) out[(size_t)(c0+ty+i)*R + (r0+tx)] = tile[tx][ty+i];
  __syncthreads();
}
__device__ void dev_tr_h(char* lds, const float* in, f16* out, int R, int C, int bx, int by){
  float (*tile)[33] = (float(*)[33])lds;
  int r0 = by*32, c0 = bx*32;
  int tx = threadIdx.x & 31, ty = threadIdx.x >> 5;
  #pragma unroll
  for (int i = 0; i < 32; i += 8) tile[ty+i][tx] = in[(size_t)(r0+ty+i)*C + (c0+tx)];
  __syncthreads();
  #pragma unroll
  for (int i = 0; i < 32; i += 8) out[(size_t)(c0+ty+i)*R + (r0+tx)] = (f16)tile[tx][ty+i];
  __syncthreads();
}

__global__ void k_init(int* flags){
  for (int i = threadIdx.x; i < 512*32; i += 256) flags[i] = 0;
}

// =================== MEGA KERNEL ===================
__global__ __launch_bounds__(256, 1) void k_all(
  const int* tok, const float* emb, const float* pos,
  const float* aiw, const float* aib, const float* aow, const float* aob,
  const float* fw1, const float* fb1, const float* fw2, const float* fb2,
  const float* n1g, const float* n1b, const float* n2g, const float* n2b,
  const float* eng, const float* enb,
  const float* V0, const float* b0, const float* V1, const float* b1,
  const float* cw1, const float* cb1, const float* cw2, const float* cb2,
  const float* gw, const float* gb_, const float* tw, const float* Rm,
  const float* og, const float* ob, const float* lmw,
  float* x, float* xn, float* qkv, float* o_, float* mid,
  float* ctx, float* ctxT, float* V0t, float* cw2t,
  float* ctxV0T, float* gctxT, float* bdg,
  f16* WAf, f16* V1tf, f16* Wc1f, f16* WDf, f16* lmw16,
  f16* hf, f16* h1f, f16* c1f, f16* gcaf,
  float* cf, float* gpre, float* tfs, int* flags, float* out)
{
  __shared__ __align__(16) char smem[147456];
  __shared__ float redbuf[4][256];
  __shared__ float normp[4][16];
  __shared__ float red[8];
  const int tid = threadIdx.x, lane = tid & 63, wid = tid >> 6;
  const int bid = blockIdx.x;
  const int l15 = lane & 15, kb = lane >> 4;
  int* afl = flags;
  int* bfl = flags + 120*32;
  int* cfl = flags + 168*32;
  int* dfl = flags + 192*32;
  int* mfl = flags + 240*32;
  int* encf = flags + 256*32;
  int eep = 0;

  // ===== P0: embed =====
  for (int m = bid; m < MR; m += GRID){
    int t = m & 63; int id = tok[m];
    const float* e = emb + (size_t)id*DD;
    const float* p = pos + (size_t)t*DD;
    float* xr = x + (size_t)m*DD;
    for (int j = tid; j < DD; j += 256) xr[j] = e[j] + p[j];
  }
  egbar(encf, ++eep);

  // ===== encoder layers =====
  for (int l = 0; l < 2; l++){
    for (int m = bid; m < MR; m += GRID)
      dev_ln(x + (size_t)m*DD, n1g + l*DD, n1b + l*DD, xn + (size_t)m*DD, nullptr, red, false);
    egbar(encf, ++eep);
    for (int tl = bid; tl < 144; tl += GRID)
      dev_gemm_tile(smem, xn, 768, aiw + (size_t)l*2304*768, 768, 2304, 2304, 768,
                    (tl % 8)*128, (tl / 8)*128, aib + l*2304, nullptr, qkv, nullptr, 1.f, 0, 0);
    egbar(encf, ++eep);
    for (int u = bid; u < 128; u += GRID) dev_attn(smem, qkv, o_, u);
    egbar(encf, ++eep);
    for (int tl = bid; tl < 48; tl += GRID)
      dev_gemm_tile(smem, o_, 768, aow + (size_t)l*768*768, 768, 768, 768, 768,
                    (tl % 8)*128, (tl / 8)*128, aob + l*768, x, x, nullptr, 1.f, 0, 0);
    egbar(encf, ++eep);
    for (int m = bid; m < MR; m += GRID)
      dev_ln(x + (size_t)m*DD, n2g + l*DD, n2b + l*DD, xn + (size_t)m*DD, nullptr, red, false);
    egbar(encf, ++eep);
    for (int tl = bid; tl < 128; tl += GRID)
      dev_gemm_tile(smem, xn, 768, fw1 + (size_t)l*2048*768, 768, 2048, 2048, 768,
                    (tl % 8)*128, (tl / 8)*128, fb1 + l*2048, nullptr, mid, nullptr, 1.f, 1, 0);
    egbar(encf, ++eep);
    for (int tl = bid; tl < 48; tl += GRID)
      dev_gemm_tile(smem, mid, 2048, fw2 + (size_t)l*768*2048, 2048, 768, 768, 2048,
                    (tl % 8)*128, (tl / 8)*128, fb2 + l*768, x, x, nullptr, 1.f, 0, 0);
    egbar(encf, ++eep);
  }
  // ===== final LN + l2norm (+ctxT) =====
  for (int m = bid; m < MR; m += GRID)
    dev_ln(x + (size_t)m*DD, eng, enb, ctx + (size_t)m*DD,
           ctxT + ((size_t)(m & 63)*16 + (m >> 6))*DD, red, true);
  egbar(encf, ++eep);

  // ===== P17: transposes + small casts + bdg (lmw cast moved to consumers) =====
  for (int task = bid; task < 5184; task += GRID){
    if (task < 2304)      dev_tr_f(smem, V0, V0t, 768, 3072, task % 96, task / 96);
    else if (task < 2880){ int t2 = task - 2304; dev_tr_f(smem, cw2, cw2t, 768, 768, t2 % 24, t2 / 24); }
    else                 { int t2 = task - 2880; dev_tr_h(smem, V1, V1tf, 3072, 768, t2 % 24, t2 / 24); }
  }
  {
    const int g0 = bid*256 + tid, stride = GRID*256;
    for (int i = g0; i < 73728; i += stride){
      float4 a = ((const float4*)cw1)[i*2]; float4 b2 = ((const float4*)cw1)[i*2+1];
      ((f16x8*)Wc1f)[i] = (f16x8){(f16)a.x,(f16)a.y,(f16)a.z,(f16)a.w,(f16)b2.x,(f16)b2.y,(f16)b2.z,(f16)b2.w};
    }
    for (int i = g0; i < 73728; i += stride){
      float4 a = ((const float4*)cw2)[i*2]; float4 b2 = ((const float4*)cw2)[i*2+1];
      ((f16x8*)WDf)[i] = (f16x8){(f16)a.x,(f16)a.y,(f16)a.z,(f16)a.w,(f16)b2.x,(f16)b2.y,(f16)b2.z,(f16)b2.w};
    }
    for (int g = g0; g < 768; g += stride){
      const float* row = gw + (size_t)g*1536 + 768;
      float s = 0.f;
      for (int j = 0; j < 768; j++) s += cb2[j]*row[j];
      bdg[g] = s;
    }
  }
  egbar(encf, ++eep);

  // ===== P18: precompute GEMMs (456 tiles) =====
  for (int task = bid; task < 456; task += GRID){
    if (task < 144)
      dev_gemm_tile(smem, V0t, 768, Rm, 768, 768, 768, 768,
                    (task % 24)*128, (task / 24)*128, nullptr, nullptr, nullptr, WAf, ALPHAF, 0, 0);
    else if (task < 180){ int t2 = task - 144;
      dev_gemm_tile(smem, tw, 768, Rm, 768, 768, 768, 768,
                    (t2 % 6)*128, (t2 / 6)*128, nullptr, nullptr, nullptr, WAf + (size_t)3072*768, ALPHAF, 0, 0); }
    else if (task < 372){ int t2 = task - 180;
      dev_gemm_tile(smem, ctx, 768, V0t, 768, 3072, 3072, 768,
                    (t2 % 8)*128, (t2 / 8)*128, b0, nullptr, ctxV0T, nullptr, 1.f, 0, 1); }
    else if (task < 420){ int t2 = task - 372;
      dev_gemm_tile(smem, ctx, 768, gw, 1536, 768, 768, 768,
                    (t2 % 8)*128, (t2 / 8)*128, nullptr, nullptr, gctxT, nullptr, 1.f, 0, 1); }
    else { int t2 = task - 420;
      dev_gemm_tile(smem, gw + 768, 1536, cw2t, 768, 768, 768, 768,
                    (t2 % 6)*128, (t2 / 6)*128, nullptr, nullptr, nullptr, WDf + (size_t)768*768, 1.f, 0, 0); }
  }
  egbar(encf, ++eep);

  // ===================== lm-head consumers =====================
  if (bid >= NWG){
    const int lw = bid - NWG;
    const int wr = (wid >> 1)*64, wc = (wid & 1)*64;
    // cast THIS WG's private lmw row-slice (overlaps with scan warmup)
    for (int nt = lw; nt < 393; nt += 120){
      int r0 = nt*128;
      int rend = r0 + 128; if (rend > LMN) rend = LMN;
      int u0 = r0*96, u1 = rend*96;           // 96 f16x8 units per row
      for (int i = u0 + tid; i < u1; i += 256){
        float4 a = ((const float4*)lmw)[(size_t)i*2];
        float4 b2 = ((const float4*)lmw)[(size_t)i*2+1];
        ((f16x8*)lmw16)[i] = (f16x8){(f16)a.x,(f16)a.y,(f16)a.z,(f16)a.w,
                                     (f16)b2.x,(f16)b2.y,(f16)b2.z,(f16)b2.w};
      }
    }
    __syncthreads();
    for (int q = 0; q < 8; ++q){
      waitf(mfl, 16, q*8 + 8);
      size_t arow[4];
      #pragma unroll
      for (int i = 0; i < 4; i++){
        int rl = wr + i*16 + l15;
        arow[i] = ((size_t)(rl >> 3)*TT + q*8 + (rl & 7))*DD + kb*8;
      }
      for (int nt = lw; nt < 393; nt += 120){
        int n0 = nt*128;
        size_t brow[4];
        #pragma unroll
        for (int j = 0; j < 4; j++){
          int n = n0 + wc + j*16 + l15;
          if (n > LMN-1) n = LMN-1;
          brow[j] = (size_t)n*LMK + kb*8;
        }
        f32x4 acc[4][4];
        #pragma unroll
        for (int i = 0; i < 4; i++)
          #pragma unroll
          for (int j = 0; j < 4; j++){ f32x4 z = {0.f,0.f,0.f,0.f}; acc[i][j] = z; }
        #pragma unroll 4
        for (int kk = 0; kk < LMK; kk += 32){
          f16x8 af[4], bf[4];
          #pragma unroll
          for (int i = 0; i < 4; i++) af[i] = ld_act16h(hf + arow[i] + kk);
          #pragma unroll
          for (int j = 0; j < 4; j++) bf[j] = *(const f16x8*)(lmw16 + brow[j] + kk);
          #pragma unroll
          for (int i = 0; i < 4; i++)
            #pragma unroll
            for (int j = 0; j < 4; j++)
              acc[i][j] = __builtin_amdgcn_mfma_f32_16x16x32_f16(af[i], bf[j], acc[i][j], 0, 0, 0);
        }
        #pragma unroll
        for (int i = 0; i < 4; i++){
          #pragma unroll
          for (int j = 0; j < 4; j++){
            #pragma unroll
            for (int r = 0; r < 4; r++){
              int ml = wr + i*16 + kb*4 + r;
              int b = ml >> 3, tt = q*8 + (ml & 7);
              int n = n0 + wc + j*16 + l15;
              if (n < LMN) out[((size_t)b*TT + tt)*LMN + n] = acc[i][j][r];
            }
          }
        }
      }
    }
    return;
  }

  // ===================== scan WGs (bids 0..119) =====================
  {
    const f16* src = WAf + (size_t)bid*32*768;
    for (int c = tid; c < 3072; c += 256){
      int row = c/96, kc = c - row*96;
      int off = (row*1536 + kc*16) ^ ((row&7)<<4);
      *(f16x8*)(smem + off) = *(const f16x8*)(src + (size_t)row*768 + kc*8);
    }
    if (bid < 48){
      const f16* s2 = V1tf + (size_t)bid*16*3072;
      for (int c = tid; c < 6144; c += 256){
        int row = c/384, kc = c - row*384;
        int off = (row*6144 + kc*16) ^ ((row&7)<<4);
        *(f16x8*)(smem + 49152 + off) = *(const f16x8*)(s2 + (size_t)row*3072 + kc*8);
      }
    } else if (bid < 72){
      const f16* s2 = Wc1f + (size_t)(bid-48)*32*768;
      for (int c = tid; c < 3072; c += 256){
        int row = c/96, kc = c - row*96;
        int off = (row*1536 + kc*16) ^ ((row&7)<<4);
        *(f16x8*)(smem + 49152 + off) = *(const f16x8*)(s2 + (size_t)row*768 + kc*8);
      }
    } else {
      const f16* s2 = WDf + (size_t)(bid-72)*32*768;
      for (int c = tid; c < 3072; c += 256){
        int row = c/96, kc = c - row*96;
        int off = (row*1536 + kc*16) ^ ((row&7)<<4);
        *(f16x8*)(smem + 49152 + off) = *(const f16x8*)(s2 + (size_t)row*768 + kc*8);
      }
    }
  }
  __syncthreads();

  const int n_a = bid*32 + (wid>>1)*16 + l15;
  float b1v = 0.f;
  if (bid < 48) b1v = b1[bid*16 + l15];
  float cpb1v = 0.f;
  if (bid >= 48 && bid < 72) cpb1v = cb1[((bid-48)*2 + (wid>>1))*16 + l15];
  float dbv = 0.f; int n_d = 0;
  if (bid >= 72){
    n_d = ((bid-72)*2 + (wid>>1))*16 + l15;
    dbv = (n_d < 768) ? cb2[n_d] : bdg[n_d - 768];
  }
  float gb3[3], og3[3], ob3[3];
  if (bid < 16){
    #pragma unroll
    for (int j = 0; j < 3; j++){
      int n = tid + j*256;
      gb3[j] = gb_[n]; og3[j] = og[n]; ob3[j] = ob[n];
    }
  }

  for (int t = 0; t < TT; ++t){
    const int ep = t + 1;
    f32x4 cv = {0.f,0.f,0.f,0.f};
    if ((wid & 1) == 0 && n_a < 3072){
      const float* p = ctxV0T + (size_t)t*16*3072 + n_a;
      #pragma unroll
      for (int r = 0; r < 4; r++) cv[r] = p[(size_t)(kb*4+r)*3072];
    }

    if (t > 0) waitf(mfl, 16, t);
    // ==== stage A
    {
      const int u = wid >> 1, kh = wid & 1;
      const int k0 = kh*384 + kb*8;
      f32x4 a = {0.f,0.f,0.f,0.f};
      if (t > 0){
        const f16* ap = hf + ((size_t)l15*TT + (t-1))*DD + k0;
        const int row = u*16 + l15, rowoff = row*1536, sw = (row&7)<<4;
        #pragma unroll
        for (int b = 0; b < 12; b++){
          int wb = (rowoff + (k0 + b*32)*2) ^ sw;
          f16x8 vb = *(const f16x8*)(smem + wb);
          f16x8 va = ld_act16h(ap + b*32);
          a = __builtin_amdgcn_mfma_f32_16x16x32_f16(va, vb, a, 0,0,0);
        }
      }
      red_store(redbuf[wid], lane, a);
    }
    __syncthreads();
    if ((wid & 1) == 0){
      f32x4 s4 = red_sum2(redbuf, lane, wid, wid+1);
      #pragma unroll
      for (int r = 0; r < 4; r++){
        int m = kb*4 + r;
        if (n_a < 3072){
          float hv = geluf(s4[r] + cv[r]);
          st_acth(h1f + (size_t)m*3072 + n_a, hv);
        } else {
          st_actf(tfs + m*DD + (n_a - 3072), s4[r]);
        }
      }
    }
    postf(afl + bid*32, ep);
    // ==== stage B
    if (bid < 48){
      waitf(afl, 120, ep);
      const int k0 = wid*768 + kb*8;
      const f16* ap = h1f + (size_t)l15*3072 + k0;
      const int rowoff = l15*6144, sw = (l15&7)<<4;
      f32x4 a = {0.f,0.f,0.f,0.f};
      #pragma unroll
      for (int b = 0; b < 24; b++){
        int wb = (rowoff + (k0 + b*32)*2) ^ sw;
        f16x8 vb = *(const f16x8*)(smem + 49152 + wb);
        f16x8 va = ld_act16h(ap + b*32);
        a = __builtin_amdgcn_mfma_f32_16x16x32_f16(va, vb, a, 0,0,0);
      }
      red_store(redbuf[wid], lane, a);
      __syncthreads();
      if (wid == 0){
        f32x4 s4 = red_sum4(redbuf, lane);
        int n = bid*16 + l15;
        #pragma unroll
        for (int r = 0; r < 4; r++){
          int m = kb*4 + r;
          st_acth(c1f + (size_t)m*DD + n, geluf(s4[r] + b1v));
        }
      }
      postf(bfl + bid*32, ep);
    }
    float gv[3], cxv[3];
    if (bid < 16){
      #pragma unroll
      for (int j = 0; j < 3; j++){
        size_t o2 = ((size_t)t*16 + bid)*DD + tid + j*256;
        gv[j] = gctxT[o2]; cxv[j] = ctxT[o2];
      }
    }
    // ==== stage C
    if (bid >= 48 && bid < 72){
      waitf(bfl, 48, ep);
      const int u = wid >> 1, kh = wid & 1;
      const int k0 = kh*384 + kb*8;
      const f16* ap = c1f + (size_t)l15*DD + k0;
      const int row = u*16 + l15, rowoff = row*1536, sw = (row&7)<<4;
      f32x4 a = {0.f,0.f,0.f,0.f};
      float sq = 0.f;
      #pragma unroll
      for (int b = 0; b < 12; b++){
        int wb = (rowoff + (k0 + b*32)*2) ^ sw;
        f16x8 vb = *(const f16x8*)(smem + 49152 + wb);
        f16x8 va = ld_act16h(ap + b*32);
        a = __builtin_amdgcn_mfma_f32_16x16x32_f16(va, vb, a, 0,0,0);
        #pragma unroll
        for (int j = 0; j < 8; j++){ float xv = (float)va[j]; sq = fmaf(xv, xv, sq); }
      }
      sq += __shfl_xor(sq,16); sq += __shfl_xor(sq,32);
      if (lane < 16) normp[wid][lane] = sq;
      red_store(redbuf[wid], lane, a);
      __syncthreads();
      if ((wid & 1) == 0){
        f32x4 s4 = red_sum2(redbuf, lane, wid, wid+1);
        int n = ((bid-48)*2 + (wid>>1))*16 + l15;
        #pragma unroll
        for (int r = 0; r < 4; r++){
          int m = kb*4 + r;
          float nm = normp[wid][m] + normp[wid+1][m];
          float inv = 1.f / fmaxf(sqrtf(nm), 1e-12f);
          st_acth(gcaf + (size_t)m*DD + n, geluf(s4[r]*inv + cpb1v));
        }
      }
      postf(cfl + (bid-48)*32, ep);
    }
    // ==== stage D
    if (bid >= 72){
      waitf(cfl, 24, ep);
      const int u = wid >> 1, kh = wid & 1;
      const int k0 = kh*384 + kb*8;
      const f16* ap = gcaf + (size_t)l15*DD + k0;
      const int row = u*16 + l15, rowoff = row*1536, sw = (row&7)<<4;
      f32x4 a = {0.f,0.f,0.f,0.f};
      #pragma unroll
      for (int b = 0; b < 12; b++){
        int wb = (rowoff + (k0 + b*32)*2) ^ sw;
        f16x8 vb = *(const f16x8*)(smem + 49152 + wb);
        f16x8 va = ld_act16h(ap + b*32);
        a = __builtin_amdgcn_mfma_f32_16x16x32_f16(va, vb, a, 0,0,0);
      }
      red_store(redbuf[wid], lane, a);
      __syncthreads();
      if ((wid & 1) == 0){
        f32x4 s4 = red_sum2(redbuf, lane, wid, wid+1);
        #pragma unroll
        for (int r = 0; r < 4; r++){
          int m = kb*4 + r;
          if (n_d < 768) st_actf(cf + m*DD + n_d, s4[r] + dbv);
          else           st_actf(gpre + m*DD + (n_d - 768), s4[r] + dbv);
        }
      }
      postf(dfl + (bid-72)*32, ep);
    }
    // ==== combine
    if (bid < 16){
      waitf(dfl, 48, ep);
      int m = bid;
      float vals[3]; float s = 0.f, ss = 0.f;
      #pragma unroll
      for (int j = 0; j < 3; j++){
        int n = tid + j*256;
        float gi = gv[j] + ld_actf(gpre + m*DD + n) + gb3[j];
        float gate = 1.f/(1.f + expf(-gi));
        float v = gate*(ld_actf(cf + m*DD + n) + ld_actf(tfs + m*DD + n)) + (1.f - gate)*cxv[j];
        vals[j] = v; s += v; ss += v*v;
      }
      #pragma unroll
      for (int o2 = 1; o2 < 64; o2 <<= 1){ s += __shfl_xor(s, o2); ss += __shfl_xor(ss, o2); }
      if (lane == 0){ red[wid] = s; red[4+wid] = ss; }
      __syncthreads();
      s  = red[0]+red[1]+red[2]+red[3];
      ss = red[4]+red[5]+red[6]+red[7];
      float mean = s*(1.f/768.f), var = ss*(1.f/768.f) - mean*mean;
      float rstd = rsqrtf(var + 1e-5f);
      #pragma unroll
      for (int j = 0; j < 3; j++){
        int n = tid + j*256;
        float y = (vals[j]-mean)*rstd*og3[j] + ob3[j];
        y = fminf(5.f, fmaxf(-5.f, y));
        st_acth(hf + ((size_t)m*TT + t)*DD + n, y);
      }
      postf(mfl + bid*32, ep);
    }
  }
}

// ---------------- host ----------------
extern "C" void kernel_launch(void* const* d_in, const int* in_sizes, int n_in,
                              void* d_out, int out_size, void* d_ws, size_t ws_size,
                              hipStream_t stream)
{
  (void)in_sizes; (void)n_in; (void)out_size; (void)ws_size;
  const int*   tok = (const int*)d_in[0];
  const float* emb = (const float*)d_in[1];
  const float* pos = (const float*)d_in[2];
  const float* aiw = (const float*)d_in[3];
  const float* aib = (const float*)d_in[4];
  const float* aow = (const float*)d_in[5];
  const float* aob = (const float*)d_in[6];
  const float* fw1 = (const float*)d_in[7];
  const float* fb1 = (const float*)d_in[8];
  const float* fw2 = (const float*)d_in[9];
  const float* fb2 = (const float*)d_in[10];
  const float* n1g = (const float*)d_in[11];
  const float* n1b = (const float*)d_in[12];
  const float* n2g = (const float*)d_in[13];
  const float* n2b = (const float*)d_in[14];
  const float* eng = (const float*)d_in[15];
  const float* enb = (const float*)d_in[16];
  const float* V0  = (const float*)d_in[17];
  const float* b0  = (const float*)d_in[18];
  const float* V1  = (const float*)d_in[19];
  const float* b1  = (const float*)d_in[20];
  const float* cw1 = (const float*)d_in[21];
  const float* cb1 = (const float*)d_in[22];
  const float* cw2 = (const float*)d_in[23];
  const float* cb2 = (const float*)d_in[24];
  const float* gw  = (const float*)d_in[25];
  const float* gb  = (const float*)d_in[26];
  const float* tw  = (const float*)d_in[27];
  const float* Rm  = (const float*)d_in[28];
  const float* og  = (const float*)d_in[29];
  const float* ob  = (const float*)d_in[30];
  const float* lmw = (const float*)d_in[31];
  float* out = (float*)d_out;

  char* base = (char*)d_ws; size_t off = 0;
  auto alloc = [&](size_t bytes)->void*{
    off = (off + 255) & ~(size_t)255; void* p = base + off; off += bytes; return p; };

  float* x     = (float*)alloc((size_t)MR*DD*4);
  float* xn    = (float*)alloc((size_t)MR*DD*4);
  float* qkv   = (float*)alloc((size_t)MR*2304*4);
  float* o_    = (float*)alloc((size_t)MR*DD*4);
  float* mid   = (float*)alloc((size_t)MR*2048*4);
  float* ctx   = (float*)alloc((size_t)MR*DD*4);
  float* ctxT  = (float*)alloc((size_t)MR*DD*4);
  float* V0t   = (float*)alloc((size_t)3072*768*4);
  float* cw2t  = (float*)alloc((size_t)768*768*4);
  float* ctxV0T= (float*)alloc((size_t)MR*3072*4);
  float* gctxT = (float*)alloc((size_t)MR*DD*4);
  float* bdg   = (float*)alloc(768*4);
  f16*   WAf   = (f16*)alloc((size_t)3840*768*2);
  f16*   V1tf  = (f16*)alloc((size_t)768*3072*2);
  f16*   Wc1f  = (f16*)alloc((size_t)768*768*2);
  f16*   WDf   = (f16*)alloc((size_t)1536*768*2);
  f16*   lmw16 = (f16*)alloc((size_t)LMN*768*2);
  f16*   hf    = (f16*)alloc((size_t)MR*DD*2);
  f16*   h1f   = (f16*)alloc((size_t)16*3072*2);
  f16*   c1f   = (f16*)alloc((size_t)16*768*2);
  f16*   gcaf  = (f16*)alloc((size_t)16*768*2);
  float* cf    = (float*)alloc((size_t)16*768*4);
  float* gpre  = (float*)alloc((size_t)16*768*4);
  float* tfs   = (float*)alloc((size_t)16*768*4);
  int*   flags = (int*)alloc((size_t)512*32*4);

  k_init<<<1, 256, 0, stream>>>(flags);
  k_all<<<GRID, 256, 0, stream>>>(tok, emb, pos, aiw, aib, aow, aob,
      fw1, fb1, fw2, fb2, n1g, n1b, n2g, n2b, eng, enb,
      V0, b0, V1, b1, cw1, cb1, cw2, cb2, gw, gb, tw, Rm, og, ob, lmw,
      x, xn, qkv, o_, mid, ctx, ctxT, V0t, cw2t, ctxV0T, gctxT, bdg,
      WAf, V1tf, Wc1f, WDf, lmw16, hf, h1f, c1f, gcaf, cf, gpre, tfs, flags, out);
}